// Round 2
// 697.291 us; speedup vs baseline: 1.0574x; 1.0574x over previous
//
#include <hip/hip_runtime.h>
#include <stdint.h>

#define B_     32
#define S_     1024
#define D_     1280
#define CROSS_ 768
#define NTOK   16
#define SCALE_ 0.125f

typedef __bf16 bf16x8 __attribute__((ext_vector_type(8)));
typedef float  f32x4  __attribute__((ext_vector_type(4)));
typedef unsigned short ushort_t;
typedef unsigned int   uint_t;

__device__ __forceinline__ float b2f(ushort_t h){ return __uint_as_float(((uint_t)h)<<16); }
__device__ __forceinline__ ushort_t f2b(float f){
  uint_t u = __float_as_uint(f);
  u += 0x7FFFu + ((u>>16)&1u);           // RNE
  return (ushort_t)(u>>16);
}
__device__ __forceinline__ uint_t pk2(float x, float y){
  return (uint_t)f2b(x) | ((uint_t)f2b(y)<<16);
}

__device__ __forceinline__ void gload_lds16(const void* g, void* l){
  __builtin_amdgcn_global_load_lds((const __attribute__((address_space(1))) void*)g,
                                   (__attribute__((address_space(3))) void*)l, 16, 0, 0);
}

// XCD-grouping swizzle: all 10 n-tiles of one m-strip land on the same XCD
// consecutively (block i -> XCD i%8 heuristic), so the A-strip stays in L2.
__device__ __forceinline__ void decode_tile(int lin, int& m0, int& n0){
  int xcd = lin & 7, slot = lin >> 3;
  int m_tile = xcd + 8*(slot/10);
  int n_tile = slot - (slot/10)*10;
  m0 = m_tile*128; n0 = n_tile*128;
}

// ------------------------------------------------------------ cvt f32->bf16
struct CvtArgs { const float* src[7]; ushort_t* dst[7]; int n[7]; };
__global__ void cvt_kernel(CvtArgs a){
  int t = blockIdx.y;
  const float* s = a.src[t]; ushort_t* d = a.dst[t]; int n = a.n[t];
  int i = (blockIdx.x*blockDim.x + threadIdx.x)*4;
  if(i >= n) return;
  float4 v = *(const float4*)(s+i);
  uint2 o; o.x = pk2(v.x,v.y); o.y = pk2(v.z,v.w);
  *(uint2*)(d+i) = o;
}

__global__ void cvt_big(const float* __restrict__ s, ushort_t* __restrict__ d, int n){
  int i = (blockIdx.x*blockDim.x + threadIdx.x)*8;
  if(i >= n) return;
  float4 v0 = *(const float4*)(s+i), v1 = *(const float4*)(s+i+4);
  uint4 o = { pk2(v0.x,v0.y), pk2(v0.z,v0.w), pk2(v1.x,v1.y), pk2(v1.z,v1.w) };
  *(uint4*)(d+i) = o;
}

// ---------------------------------------------------------------- gates ----
__global__ void gates_kernel(const float* __restrict__ enc,
                             const float* __restrict__ w_gate,
                             const float* __restrict__ b_gate,
                             const float* __restrict__ aLog,
                             const float* __restrict__ dLog,
                             float* __restrict__ gates){
  int b = blockIdx.x, tid = threadIdx.x;
  __shared__ float red[256];
  float acc = 0.f;
  for(int k = tid; k < CROSS_; k += 256){
    float s = 0.f;
    for(int t = 0; t < NTOK; ++t)
      s += enc[(size_t)(b*48 + t)*CROSS_ + k];       // dis tokens = enc[:, :16]
    acc += w_gate[k] * s;
  }
  red[tid] = acc; __syncthreads();
  for(int off = 128; off > 0; off >>= 1){
    if(tid < off) red[tid] += red[tid+off];
    __syncthreads();
  }
  if(tid == 0){
    float shift = red[0]*(1.f/16.f) + b_gate[0];
    gates[b*2+0] = 1.f/(1.f+__expf(shift - aLog[0]));     // sigmoid(aLog - shift)
    gates[b*2+1] = 1.f/(1.f+__expf(-(dLog[0] + shift)));  // sigmoid(dLog + shift)
  }
}

// --------------------------------------------------------------- kv gemm ---
// C[tau][b][t][n] = tokens(tau) @ W(tau)^T ; M=512 (b*16+t), N=1280, K=768
__global__ __launch_bounds__(256) void kv_gemm(const ushort_t* __restrict__ enc,
      const ushort_t* __restrict__ wk,  const ushort_t* __restrict__ wv,
      const ushort_t* __restrict__ wkd, const ushort_t* __restrict__ wvd,
      ushort_t* __restrict__ kv){
  __shared__ __align__(16) ushort_t As[128*64];
  __shared__ __align__(16) ushort_t Bs[128*64];
  const int tau = blockIdx.z;
  const ushort_t* W = (tau==0)? wk : (tau==1)? wv : (tau==2)? wkd : wvd;
  const int tok_off = (tau < 2) ? NTOK : 0;   // anat = enc[:,16:32], dis = enc[:,0:16]
  const int m0 = blockIdx.x*128, n0 = blockIdx.y*128;
  const int tid = threadIdx.x, l = tid & 63, w = tid >> 6;
  const int wm = (w&1)*64, wn = (w>>1)*64;
  const f32x4 fz = {0.f,0.f,0.f,0.f};
  f32x4 acc[4][4];
  #pragma unroll
  for(int i=0;i<4;++i){
    #pragma unroll
    for(int j=0;j<4;++j) acc[i][j] = fz;
  }
  for(int kt = 0; kt < CROSS_/64; ++kt){
    const int k0 = kt*64;
    #pragma unroll
    for(int i=0;i<4;++i){
      int row = (w*4+i)*8 + (l>>3);
      int c   = l & 7;
      int gm  = m0 + row;
      int er  = (gm>>4)*48 + tok_off + (gm&15);
      gload_lds16(enc + (size_t)er*CROSS_ + k0 + c*8, As + (w*4+i)*512);
      gload_lds16(W  + (size_t)(n0+row)*CROSS_ + k0 + c*8, Bs + (w*4+i)*512);
    }
    __syncthreads();
    #pragma unroll
    for(int ks = 0; ks < 64; ks += 32){
      bf16x8 a[4], bq[4];
      #pragma unroll
      for(int i=0;i<4;++i) a[i]  = *(const bf16x8*)&As[(wm+i*16+(l&15))*64 + ks + (l>>4)*8];
      #pragma unroll
      for(int j=0;j<4;++j) bq[j] = *(const bf16x8*)&Bs[(wn+j*16+(l&15))*64 + ks + (l>>4)*8];
      #pragma unroll
      for(int i=0;i<4;++i){
        #pragma unroll
        for(int j=0;j<4;++j)
          acc[i][j] = __builtin_amdgcn_mfma_f32_16x16x32_bf16(a[i], bq[j], acc[i][j], 0,0,0);
      }
    }
    __syncthreads();
  }
  #pragma unroll
  for(int i=0;i<4;++i){
    #pragma unroll
    for(int j=0;j<4;++j){
      #pragma unroll
      for(int r=0;r<4;++r){
        int m = m0 + wm + i*16 + (l>>4)*4 + r;
        int n = n0 + wn + j*16 + (l&15);
        int b = m >> 4, t = m & 15;
        kv[(((size_t)tau*B_ + b)*NTOK + t)*D_ + n] = f2b(acc[i][j][r]);
      }
    }
  }
}

// ------------------------------------------------- gemm1 + fused attention -
// q = X @ Wq^T for a 128x128 tile (= 128 s-rows x 2 heads), then attention
// against 16 anat + 16 dis keys, gated mix, z written bf16 to Z.
__global__ __launch_bounds__(256,3) void gemm1_attn(
      const ushort_t* __restrict__ X, const ushort_t* __restrict__ Wq,
      const ushort_t* __restrict__ kv, const float* __restrict__ gates,
      ushort_t* __restrict__ Z){
  __shared__ __align__(16) union {
    struct { ushort_t As[128*64]; ushort_t Bs[128*64]; } st;              // 32768 B
    struct { union { ushort_t qs[128*132];                                // 33792 B
                     ushort_t ps[4][64*44]; } u;                          // 22528 B
             ushort_t ks[2*2*16*72];                                      //  9216 B
             ushort_t vts[2*64*40]; } ep;                                 // 10240 B
  } sm;                                                                   // 53248 B -> 3 blk/CU
  int m0, n0; decode_tile(blockIdx.x, m0, n0);
  const int tid = threadIdx.x, l = tid & 63, w = tid >> 6;
  const int wm = (w&1)*64, wn = (w>>1)*64;
  const int b = m0 >> 10;                       // 1024 rows per batch
  const f32x4 fz = {0.f,0.f,0.f,0.f};
  f32x4 acc[4][4];
  #pragma unroll
  for(int i=0;i<4;++i){
    #pragma unroll
    for(int j=0;j<4;++j) acc[i][j] = fz;
  }
  for(int kt = 0; kt < D_/64; ++kt){
    const int k0 = kt*64;
    #pragma unroll
    for(int i=0;i<4;++i){
      int row = (w*4+i)*8 + (l>>3);
      int c   = l & 7;
      gload_lds16(X  + (size_t)(m0+row)*D_ + k0 + c*8, sm.st.As + (w*4+i)*512);
      gload_lds16(Wq + (size_t)(n0+row)*D_ + k0 + c*8, sm.st.Bs + (w*4+i)*512);
    }
    __syncthreads();
    #pragma unroll
    for(int ks = 0; ks < 64; ks += 32){
      bf16x8 a[4], bq[4];
      #pragma unroll
      for(int i=0;i<4;++i) a[i]  = *(const bf16x8*)&sm.st.As[(wm+i*16+(l&15))*64 + ks + (l>>4)*8];
      #pragma unroll
      for(int j=0;j<4;++j) bq[j] = *(const bf16x8*)&sm.st.Bs[(wn+j*16+(l&15))*64 + ks + (l>>4)*8];
      #pragma unroll
      for(int i=0;i<4;++i){
        #pragma unroll
        for(int j=0;j<4;++j)
          acc[i][j] = __builtin_amdgcn_mfma_f32_16x16x32_bf16(a[i], bq[j], acc[i][j], 0,0,0);
      }
    }
    __syncthreads();
  }
  // --- epilogue: q tile -> LDS (bf16), stage K (row-major) and V^T ---------
  #pragma unroll
  for(int i=0;i<4;++i){
    #pragma unroll
    for(int j=0;j<4;++j){
      #pragma unroll
      for(int r=0;r<4;++r)
        sm.ep.u.qs[(wm+i*16+(l>>4)*4+r)*132 + wn + j*16 + (l&15)] = f2b(acc[i][j][r]);
    }
  }
  // K: ks[h][tk][t][d]  (tk: 0=k_anat(tensor0), 1=k_dis(tensor2))
  for(int id = tid; id < 512; id += 256){
    int h  = id >> 8, rem = id & 255;
    int tk = rem >> 7, t = (rem>>3)&15, c = rem&7;
    int tensor = tk*2;
    const ushort_t* src = kv + (((size_t)tensor*B_ + b)*NTOK + t)*D_ + n0 + h*64 + c*8;
    *(uint4*)&sm.ep.ks[((h*2+tk)*16 + t)*72 + c*8] = *(const uint4*)src;
  }
  // V^T: vts[h][d][t'] with t' = t + 16*(dis)  (tensor 1 = v_anat, 3 = v_dis)
  for(int id = tid; id < 512; id += 256){
    int h = id >> 8, rem = id & 255;
    int tp = rem >> 3, c = rem & 7;
    int tensor = (tp < 16) ? 1 : 3;
    int t = tp & 15;
    const ushort_t* src = kv + (((size_t)tensor*B_ + b)*NTOK + t)*D_ + n0 + h*64 + c*8;
    uint4 v = *(const uint4*)src;
    const ushort_t* pv = (const ushort_t*)&v;
    #pragma unroll
    for(int e=0;e<8;++e) sm.ep.vts[(h*64 + c*8 + e)*40 + tp] = pv[e];
  }
  __syncthreads();
  // --- scores: QK^T via MFMA (wave = one head h, 64 s-rows) ---------------
  const int h = w >> 1, ws0 = (w&1)*64;
  const float gA = gates[b*2+0], gD = gates[b*2+1];
  f32x4 scA[4], scD[4];
  #pragma unroll
  for(int i=0;i<4;++i){ scA[i] = fz; scD[i] = fz; }
  #pragma unroll
  for(int ks0 = 0; ks0 < 64; ks0 += 32){
    bf16x8 qf[4];
    #pragma unroll
    for(int i=0;i<4;++i)
      qf[i] = *(const bf16x8*)&sm.ep.u.qs[(ws0+i*16+(l&15))*132 + h*64 + ks0 + (l>>4)*8];
    bf16x8 kA = *(const bf16x8*)&sm.ep.ks[((h*2+0)*16 + (l&15))*72 + ks0 + (l>>4)*8];
    bf16x8 kD = *(const bf16x8*)&sm.ep.ks[((h*2+1)*16 + (l&15))*72 + ks0 + (l>>4)*8];
    #pragma unroll
    for(int i=0;i<4;++i){
      scA[i] = __builtin_amdgcn_mfma_f32_16x16x32_bf16(qf[i], kA, scA[i], 0,0,0);
      scD[i] = __builtin_amdgcn_mfma_f32_16x16x32_bf16(qf[i], kD, scD[i], 0,0,0);
    }
  }
  __syncthreads();   // qs region dead; reuse for per-wave ps
  // --- softmax over 16 keys (t = lane&15), separate per tensor, gated -----
  #pragma unroll
  for(int i=0;i<4;++i){
    #pragma unroll
    for(int r=0;r<4;++r){
      float vA = scA[i][r]*SCALE_, vD = scD[i][r]*SCALE_;
      float mA = vA, mD = vD;
      #pragma unroll
      for(int off=1; off<16; off<<=1){
        mA = fmaxf(mA, __shfl_xor(mA, off));
        mD = fmaxf(mD, __shfl_xor(mD, off));
      }
      float eA = __expf(vA - mA), eD = __expf(vD - mD);
      float sA = eA, sD = eD;
      #pragma unroll
      for(int off=1; off<16; off<<=1){
        sA += __shfl_xor(sA, off);
        sD += __shfl_xor(sD, off);
      }
      int lr = i*16 + (l>>4)*4 + r;           // local row within wave's strip
      sm.ep.u.ps[w][lr*44 + 0  + (l&15)] = f2b(gA*eA/sA);
      sm.ep.u.ps[w][lr*44 + 16 + (l&15)] = f2b(gD*eD/sD);
    }
  }
  // --- PV: [gA*P_A | gD*P_D] (64x32) @ [V_A;V_D] (32x64), K=32 one MFMA ---
  f32x4 z[4][4];
  #pragma unroll
  for(int i=0;i<4;++i){
    #pragma unroll
    for(int j=0;j<4;++j) z[i][j] = fz;
  }
  bf16x8 pa[4], vb[4];
  #pragma unroll
  for(int i=0;i<4;++i) pa[i] = *(const bf16x8*)&sm.ep.u.ps[w][(i*16+(l&15))*44 + (l>>4)*8];
  #pragma unroll
  for(int j=0;j<4;++j) vb[j] = *(const bf16x8*)&sm.ep.vts[(h*64 + j*16 + (l&15))*40 + (l>>4)*8];
  #pragma unroll
  for(int i=0;i<4;++i){
    #pragma unroll
    for(int j=0;j<4;++j)
      z[i][j] = __builtin_amdgcn_mfma_f32_16x16x32_bf16(pa[i], vb[j], z[i][j], 0,0,0);
  }
  #pragma unroll
  for(int i=0;i<4;++i){
    #pragma unroll
    for(int j=0;j<4;++j){
      #pragma unroll
      for(int r=0;r<4;++r){
        int row = m0 + ws0 + i*16 + (l>>4)*4 + r;
        int col = n0 + h*64 + j*16 + (l&15);
        Z[(size_t)row*D_ + col] = f2b(z[i][j][r]);
      }
    }
  }
}

// ----------------------------------------------- gemm2: 256^2 8-phase ------
// out = Z @ Wo^T + bias + resid.  M=32768, N=1280, K=1280.
// BM=BN=256, BK=64, 512 threads (8 waves, 2Mx4N), double-buffered LDS 128 KiB.
//
// Staging is split into CONSUMPTION-ORDER groups so counted vmcnt is exact
// (2 load-instructions/wave per group, FIFO vmcnt per m135):
//   S0 = A rows [0,64) of both halves        -> read at p0 (DS_A(0))
//   S1 = B rows ==[0,32) mod 64, both halves -> read at p0 (DS_B(0)), p2
//   S2 = B rows ==[32,64) mod 64             -> read at p1 (DS_B(1)), p3
//   S3 = A rows [64,128) of both halves      -> read at p2 (DS_A(1))
// Iter t issues S0..S3 of tile t+1 at p0..p3.  Queue invariant at loop top:
// [S2(cur),S3(cur)] outstanding, S0/S1(cur) verified.  VMW(4)@p0 verifies
// S2(cur); @p1 verifies S3(cur); @p3 verifies S0,S1(next).  Never drains
// below 4 in the main loop; tail drains 2 -> 0.
#define VMW(n)  asm volatile("s_waitcnt vmcnt(" #n ")" ::: "memory")
#define FENCE() asm volatile("" ::: "memory")
#define BARX()  do{ FENCE(); __builtin_amdgcn_s_barrier(); FENCE(); }while(0)

// one 64x64 A quarter (8KB = 512thr x 16B): LDS linear, source col pre-XORed
__device__ __forceinline__ void stage_aq(const ushort_t* __restrict__ g,
                                         ushort_t* le, int tid){
  int row = tid >> 3;                       // 0..63 (region base is mult of 8)
  int c   = ((tid & 7) ^ (row & 7)) << 3;   // pre-swizzled col chunk
  gload_lds16(g + (size_t)row*D_ + c, le + (tid>>6)*512);
}
// two 32-row B slabs within one 128-row half: rows [s0,s0+32) and [s0+64,s0+96)
__device__ __forceinline__ void stage_b2(const ushort_t* __restrict__ g,
                                         ushort_t* lh, int s0, int tid){
  int w   = tid >> 6;
  int blk = w >> 2;                         // waves 0-3 -> slab s0, 4-7 -> s0+64
  int t   = tid & 255;
  int rr  = s0 + blk*64 + (t >> 3);         // row within half (mult-of-8 bases)
  int c   = ((t & 7) ^ (rr & 7)) << 3;
  gload_lds16(g + (size_t)rr*D_ + c, lh + (s0 + blk*64)*64 + (w&3)*512);
}

__global__ __launch_bounds__(512,2) void gemm2_8p(
      const ushort_t* __restrict__ Zin, const ushort_t* __restrict__ Wo,
      const float* __restrict__ bias, const float* __restrict__ resid,
      float* __restrict__ out){
  __shared__ __align__(16) ushort_t lds[65536];   // A[2][2][128][64] | B same
  // bijective XCD swizzle: 640 blocks, 640%8==0 -> each XCD owns 80
  // consecutive logical tiles (16 m-strips x 5 n-tiles) -> A-strips + the
  // whole Wo panel stay in its L2.
  const int lid = (blockIdx.x & 7)*80 + (blockIdx.x >> 3);
  const int m0 = (lid/5)*256, n0 = (lid%5)*256;
  const int tid = threadIdx.x, l = tid & 63, w = tid >> 6;
  const int wr = w >> 2, wc = w & 3;            // wave -> 128x64 output sub-tile
  const int lr = l & 15;
  const int csw0 = ((l>>4)*8)      ^ ((l&7)<<3);   // swizzled k-col, ks=0
  const int csw1 = (32+(l>>4)*8)   ^ ((l&7)<<3);   // swizzled k-col, ks=32
  const int bro  = (wc & 1)*64 + lr;               // B row base within half
  const ushort_t* Asrc = Zin + (size_t)m0*D_;
  const ushort_t* Bsrc = Wo  + (size_t)n0*D_;
  const f32x4 fz = {0.f,0.f,0.f,0.f};
  f32x4 acc[8][4];
  #pragma unroll
  for(int i=0;i<8;++i){
    #pragma unroll
    for(int j=0;j<4;++j) acc[i][j] = fz;
  }
  bf16x8 a[4][2], bb[2][2];

#define AB(tt) (lds + ((tt)&1)*16384)
#define BB(tt) (lds + 32768 + ((tt)&1)*16384)
#define ST_S0(tt) { stage_aq(Asrc + (size_t)  0*D_ + (tt)*64, AB(tt),          tid); \
                    stage_aq(Asrc + (size_t)128*D_ + (tt)*64, AB(tt) + 8192,   tid); }
#define ST_S1(tt) { stage_b2(Bsrc + (size_t)  0*D_ + (tt)*64, BB(tt),        0, tid); \
                    stage_b2(Bsrc + (size_t)128*D_ + (tt)*64, BB(tt) + 8192, 0, tid); }
#define ST_S2(tt) { stage_b2(Bsrc + (size_t)  0*D_ + (tt)*64, BB(tt),       32, tid); \
                    stage_b2(Bsrc + (size_t)128*D_ + (tt)*64, BB(tt) + 8192,32, tid); }
#define ST_S3(tt) { stage_aq(Asrc + (size_t) 64*D_ + (tt)*64, AB(tt) + 4096,  tid); \
                    stage_aq(Asrc + (size_t)192*D_ + (tt)*64, AB(tt) + 12288, tid); }
#define DS_A(qi, Ab) { _Pragma("unroll") for(int i=0;i<4;++i){ \
      a[i][0] = *(const bf16x8*)&(Ab)[((qi)*64 + i*16 + lr)*64 + csw0]; \
      a[i][1] = *(const bf16x8*)&(Ab)[((qi)*64 + i*16 + lr)*64 + csw1]; } }
#define DS_B(qj, Bb) { _Pragma("unroll") for(int j=0;j<2;++j){ \
      bb[j][0] = *(const bf16x8*)&(Bb)[(bro + ((qj)*2+j)*16)*64 + csw0]; \
      bb[j][1] = *(const bf16x8*)&(Bb)[(bro + ((qj)*2+j)*16)*64 + csw1]; } }
#define MM(qi,qj) { __builtin_amdgcn_s_setprio(1); \
    _Pragma("unroll") for(int i=0;i<4;++i){ _Pragma("unroll") for(int j=0;j<2;++j){ \
      acc[(qi)*4+i][(qj)*2+j] = __builtin_amdgcn_mfma_f32_16x16x32_bf16(a[i][0], bb[j][0], acc[(qi)*4+i][(qj)*2+j],0,0,0); \
      acc[(qi)*4+i][(qj)*2+j] = __builtin_amdgcn_mfma_f32_16x16x32_bf16(a[i][1], bb[j][1], acc[(qi)*4+i][(qj)*2+j],0,0,0); } } \
    __builtin_amdgcn_s_setprio(0); }

  // prologue: tile 0 in consumption order; VMW(4) verifies exactly S0,S1.
  ST_S0(0); ST_S1(0); ST_S2(0); ST_S3(0);
  VMW(4);
  BARX();
  for(int t = 0; t < 19; ++t){
    const ushort_t* Ab = AB(t) + wr*8192;
    const ushort_t* Bb = BB(t) + (wc>>1)*8192;
    // p0: reads S0,S1(cur) [verified @ prev p3]; verify S2(cur) for p1.
    DS_A(0,Ab); DS_B(0,Bb); ST_S0(t+1); VMW(4); BARX(); MM(0,0); BARX();
    // p1: reads S2(cur); verify S3(cur) for p2.
    DS_B(1,Bb);             ST_S1(t+1); VMW(4); BARX(); MM(0,1); BARX();
    // p2: reads S3(cur) + S1 re-read; no deadline here.
    DS_A(1,Ab); DS_B(0,Bb); ST_S2(t+1);         BARX(); MM(1,0); BARX();
    // p3: reads S2 re-read; verify S0,S1(next) for next p0.
    DS_B(1,Bb);             ST_S3(t+1); VMW(4); BARX(); MM(1,1); BARX();
  }
  { // tail: tile 19, no prefetch; drain 2 -> 0.
    const ushort_t* Ab = AB(19) + wr*8192;
    const ushort_t* Bb = BB(19) + (wc>>1)*8192;
    DS_A(0,Ab); DS_B(0,Bb); VMW(2); BARX(); MM(0,0); BARX();
    DS_B(1,Bb);             VMW(0); BARX(); MM(0,1); BARX();
    DS_A(1,Ab); DS_B(0,Bb);         BARX(); MM(1,0); BARX();
    DS_B(1,Bb);                             MM(1,1);
  }
  // epilogue: bias + residual, f32 out
  float bj[4];
  #pragma unroll
  for(int j=0;j<4;++j) bj[j] = bias[n0 + wc*64 + j*16 + lr];
  #pragma unroll
  for(int i=0;i<8;++i){
    #pragma unroll
    for(int j=0;j<4;++j){
      #pragma unroll
      for(int r=0;r<4;++r){
        int m = m0 + wr*128 + i*16 + (l>>4)*4 + r;
        int n = n0 + wc*64 + j*16 + lr;
        out[(size_t)m*D_ + n] = acc[i][j][r] + bj[j] + resid[(size_t)m*D_ + n];
      }
    }
  }
#undef AB
#undef BB
#undef ST_S0
#undef ST_S1
#undef ST_S2
#undef ST_S3
#undef DS_A
#undef DS_B
#undef MM
}

// --------------------------------------------------------------------------
extern "C" void kernel_launch(void* const* d_in, const int* in_sizes, int n_in,
                              void* d_out, int out_size, void* d_ws, size_t ws_size,
                              hipStream_t stream){
  const float* hidden = (const float*)d_in[0];
  const float* enc    = (const float*)d_in[1];
  const float* w_q    = (const float*)d_in[2];
  const float* w_k    = (const float*)d_in[3];
  const float* w_v    = (const float*)d_in[4];
  const float* w_kd   = (const float*)d_in[5];
  const float* w_vd   = (const float*)d_in[6];
  const float* w_gate = (const float*)d_in[7];
  const float* b_gate = (const float*)d_in[8];
  const float* aLog   = (const float*)d_in[9];
  const float* dLog   = (const float*)d_in[10];
  const float* w_out  = (const float*)d_in[11];
  const float* b_out  = (const float*)d_in[12];
  float* out = (float*)d_out;

  char* ws = (char*)d_ws;
  ushort_t* z_bf   = (ushort_t*)(ws + 0);           // 83,886,080 B
  ushort_t* kv_bf  = (ushort_t*)(ws + 83886080);    //  5,242,880 B
  ushort_t* wq_bf  = (ushort_t*)(ws + 89128960);    //  3,276,800 B
  ushort_t* wk_bf  = (ushort_t*)(ws + 92405760);    //  1,966,080 B
  ushort_t* wv_bf  = (ushort_t*)(ws + 94371840);    //  1,966,080 B
  ushort_t* wkd_bf = (ushort_t*)(ws + 96337920);    //  1,966,080 B
  ushort_t* wvd_bf = (ushort_t*)(ws + 98304000);    //  1,966,080 B
  ushort_t* wo_bf  = (ushort_t*)(ws + 100270080);   //  3,276,800 B
  ushort_t* enc_bf = (ushort_t*)(ws + 103546880);   //  2,359,296 B
  float*    gates  = (float*)   (ws + 105906176);   //        256 B

  // hidden bf16 lives in the FIRST HALF OF d_out (168 MB f32 buffer; gemm1
  // consumes it fully before gemm2 writes d_out — stream-ordered, safe).
  ushort_t* hid_bf = (ushort_t*)d_out;              // 83,886,080 B <= out bytes

  CvtArgs ca;
  ca.src[0]=w_q;   ca.dst[0]=wq_bf;  ca.n[0]=D_*D_;
  ca.src[1]=w_k;   ca.dst[1]=wk_bf;  ca.n[1]=D_*CROSS_;
  ca.src[2]=w_v;   ca.dst[2]=wv_bf;  ca.n[2]=D_*CROSS_;
  ca.src[3]=w_kd;  ca.dst[3]=wkd_bf; ca.n[3]=D_*CROSS_;
  ca.src[4]=w_vd;  ca.dst[4]=wvd_bf; ca.n[4]=D_*CROSS_;
  ca.src[5]=w_out; ca.dst[5]=wo_bf;  ca.n[5]=D_*D_;
  ca.src[6]=enc;   ca.dst[6]=enc_bf; ca.n[6]=B_*48*CROSS_;
  cvt_kernel<<<dim3(1600,7), 256, 0, stream>>>(ca);
  cvt_big<<<20480, 256, 0, stream>>>(hidden, hid_bf, B_*S_*D_);

  gates_kernel<<<32, 256, 0, stream>>>(enc, w_gate, b_gate, aLog, dLog, gates);
  kv_gemm<<<dim3(4,10,4), 256, 0, stream>>>(enc_bf, wk_bf, wv_bf, wkd_bf, wvd_bf, kv_bf);
  gemm1_attn<<<2560, 256, 0, stream>>>(hid_bf, wq_bf, kv_bf, gates, z_bf);
  gemm2_8p<<<640, 512, 0, stream>>>(z_bf, wo_bf, b_out, hidden, out);
}

// Round 3
// 666.431 us; speedup vs baseline: 1.1063x; 1.0463x over previous
//
#include <hip/hip_runtime.h>
#include <stdint.h>

#define B_     32
#define S_     1024
#define D_     1280
#define CROSS_ 768
#define NTOK   16
#define SCALE_ 0.125f

typedef __bf16 bf16x8 __attribute__((ext_vector_type(8)));
typedef float  f32x4  __attribute__((ext_vector_type(4)));
typedef unsigned short ushort_t;
typedef unsigned int   uint_t;

__device__ __forceinline__ float b2f(ushort_t h){ return __uint_as_float(((uint_t)h)<<16); }
__device__ __forceinline__ ushort_t f2b(float f){
  uint_t u = __float_as_uint(f);
  u += 0x7FFFu + ((u>>16)&1u);           // RNE
  return (ushort_t)(u>>16);
}
__device__ __forceinline__ uint_t pk2(float x, float y){
  return (uint_t)f2b(x) | ((uint_t)f2b(y)<<16);
}

__device__ __forceinline__ void gload_lds16(const void* g, void* l){
  __builtin_amdgcn_global_load_lds((const __attribute__((address_space(1))) void*)g,
                                   (__attribute__((address_space(3))) void*)l, 16, 0, 0);
}

// ------------------------------------------------------------ cvt f32->bf16
struct CvtArgs { const float* src[7]; ushort_t* dst[7]; int n[7]; };
__global__ void cvt_kernel(CvtArgs a){
  int t = blockIdx.y;
  const float* s = a.src[t]; ushort_t* d = a.dst[t]; int n = a.n[t];
  int i = (blockIdx.x*blockDim.x + threadIdx.x)*4;
  if(i >= n) return;
  float4 v = *(const float4*)(s+i);
  uint2 o; o.x = pk2(v.x,v.y); o.y = pk2(v.z,v.w);
  *(uint2*)(d+i) = o;
}

__global__ void cvt_big(const float* __restrict__ s, ushort_t* __restrict__ d, int n){
  int i = (blockIdx.x*blockDim.x + threadIdx.x)*8;
  if(i >= n) return;
  float4 v0 = *(const float4*)(s+i), v1 = *(const float4*)(s+i+4);
  uint4 o = { pk2(v0.x,v0.y), pk2(v0.z,v0.w), pk2(v1.x,v1.y), pk2(v1.z,v1.w) };
  *(uint4*)(d+i) = o;
}

// ---------------------------------------------------------------- gates ----
__global__ void gates_kernel(const float* __restrict__ enc,
                             const float* __restrict__ w_gate,
                             const float* __restrict__ b_gate,
                             const float* __restrict__ aLog,
                             const float* __restrict__ dLog,
                             float* __restrict__ gates){
  int b = blockIdx.x, tid = threadIdx.x;
  __shared__ float red[256];
  float acc = 0.f;
  for(int k = tid; k < CROSS_; k += 256){
    float s = 0.f;
    for(int t = 0; t < NTOK; ++t)
      s += enc[(size_t)(b*48 + t)*CROSS_ + k];       // dis tokens = enc[:, :16]
    acc += w_gate[k] * s;
  }
  red[tid] = acc; __syncthreads();
  for(int off = 128; off > 0; off >>= 1){
    if(tid < off) red[tid] += red[tid+off];
    __syncthreads();
  }
  if(tid == 0){
    float shift = red[0]*(1.f/16.f) + b_gate[0];
    gates[b*2+0] = 1.f/(1.f+__expf(shift - aLog[0]));     // sigmoid(aLog - shift)
    gates[b*2+1] = 1.f/(1.f+__expf(-(dLog[0] + shift)));  // sigmoid(dLog + shift)
  }
}

// --------------------------------------------------------------- kv gemm ---
// C[tau][b][t][n] = tokens(tau) @ W(tau)^T ; M=512 (b*16+t), N=1280, K=768
__global__ __launch_bounds__(256) void kv_gemm(const ushort_t* __restrict__ enc,
      const ushort_t* __restrict__ wk,  const ushort_t* __restrict__ wv,
      const ushort_t* __restrict__ wkd, const ushort_t* __restrict__ wvd,
      ushort_t* __restrict__ kv){
  __shared__ __align__(16) ushort_t As[128*64];
  __shared__ __align__(16) ushort_t Bs[128*64];
  const int tau = blockIdx.z;
  const ushort_t* W = (tau==0)? wk : (tau==1)? wv : (tau==2)? wkd : wvd;
  const int tok_off = (tau < 2) ? NTOK : 0;   // anat = enc[:,16:32], dis = enc[:,0:16]
  const int m0 = blockIdx.x*128, n0 = blockIdx.y*128;
  const int tid = threadIdx.x, l = tid & 63, w = tid >> 6;
  const int wm = (w&1)*64, wn = (w>>1)*64;
  const f32x4 fz = {0.f,0.f,0.f,0.f};
  f32x4 acc[4][4];
  #pragma unroll
  for(int i=0;i<4;++i){
    #pragma unroll
    for(int j=0;j<4;++j) acc[i][j] = fz;
  }
  for(int kt = 0; kt < CROSS_/64; ++kt){
    const int k0 = kt*64;
    #pragma unroll
    for(int i=0;i<4;++i){
      int row = (w*4+i)*8 + (l>>3);
      int c   = l & 7;
      int gm  = m0 + row;
      int er  = (gm>>4)*48 + tok_off + (gm&15);
      gload_lds16(enc + (size_t)er*CROSS_ + k0 + c*8, As + (w*4+i)*512);
      gload_lds16(W  + (size_t)(n0+row)*CROSS_ + k0 + c*8, Bs + (w*4+i)*512);
    }
    __syncthreads();
    #pragma unroll
    for(int ks = 0; ks < 64; ks += 32){
      bf16x8 a[4], bq[4];
      #pragma unroll
      for(int i=0;i<4;++i) a[i]  = *(const bf16x8*)&As[(wm+i*16+(l&15))*64 + ks + (l>>4)*8];
      #pragma unroll
      for(int j=0;j<4;++j) bq[j] = *(const bf16x8*)&Bs[(wn+j*16+(l&15))*64 + ks + (l>>4)*8];
      #pragma unroll
      for(int i=0;i<4;++i){
        #pragma unroll
        for(int j=0;j<4;++j)
          acc[i][j] = __builtin_amdgcn_mfma_f32_16x16x32_bf16(a[i], bq[j], acc[i][j], 0,0,0);
      }
    }
    __syncthreads();
  }
  #pragma unroll
  for(int i=0;i<4;++i){
    #pragma unroll
    for(int j=0;j<4;++j){
      #pragma unroll
      for(int r=0;r<4;++r){
        int m = m0 + wm + i*16 + (l>>4)*4 + r;
        int n = n0 + wn + j*16 + (l&15);
        int b = m >> 4, t = m & 15;
        kv[(((size_t)tau*B_ + b)*NTOK + t)*D_ + n] = f2b(acc[i][j][r]);
      }
    }
  }
}

// ---------------------------------------------------------------------------
// Shared pieces of the 256^2 8-phase mainloop (T2 swizzle via pre-XORed
// global source + XORed ds_read; T4 counted vmcnt; T5 setprio).
#define VMW(n)  asm volatile("s_waitcnt vmcnt(" #n ")" ::: "memory")
#define FENCE() asm volatile("" ::: "memory")
#define BARX()  do{ FENCE(); __builtin_amdgcn_s_barrier(); FENCE(); }while(0)
#define LGKM0() asm volatile("s_waitcnt lgkmcnt(0)" ::: "memory")

// one 64x64 A quarter (8KB = 512thr x 16B): LDS linear, source col pre-XORed
__device__ __forceinline__ void stage_aq(const ushort_t* __restrict__ g,
                                         ushort_t* le, int tid){
  int row = tid >> 3;                       // 0..63 (region base is mult of 8)
  int c   = ((tid & 7) ^ (row & 7)) << 3;   // pre-swizzled col chunk
  gload_lds16(g + (size_t)row*D_ + c, le + (tid>>6)*512);
}
// two 32-row B slabs within one 128-row half: rows [s0,s0+32) and [s0+64,s0+96)
__device__ __forceinline__ void stage_b2(const ushort_t* __restrict__ g,
                                         ushort_t* lh, int s0, int tid){
  int w   = tid >> 6;
  int blk = w >> 2;                         // waves 0-3 -> slab s0, 4-7 -> s0+64
  int t   = tid & 255;
  int rr  = s0 + blk*64 + (t >> 3);         // row within half (mult-of-8 bases)
  int c   = ((t & 7) ^ (rr & 7)) << 3;
  gload_lds16(g + (size_t)rr*D_ + c, lh + (s0 + blk*64)*64 + (w&3)*512);
}

#define AB(tt) (lds + ((tt)&1)*16384)
#define BB(tt) (lds + 32768 + ((tt)&1)*16384)
#define ST_S0(tt) { stage_aq(Asrc + (size_t)  0*D_ + (tt)*64, AB(tt),          tid); \
                    stage_aq(Asrc + (size_t)128*D_ + (tt)*64, AB(tt) + 8192,   tid); }
#define ST_S1(tt) { stage_b2(Bsrc + (size_t)  0*D_ + (tt)*64, BB(tt),        0, tid); \
                    stage_b2(Bsrc + (size_t)128*D_ + (tt)*64, BB(tt) + 8192, 0, tid); }
#define ST_S2(tt) { stage_b2(Bsrc + (size_t)  0*D_ + (tt)*64, BB(tt),       32, tid); \
                    stage_b2(Bsrc + (size_t)128*D_ + (tt)*64, BB(tt) + 8192,32, tid); }
#define ST_S3(tt) { stage_aq(Asrc + (size_t) 64*D_ + (tt)*64, AB(tt) + 4096,  tid); \
                    stage_aq(Asrc + (size_t)192*D_ + (tt)*64, AB(tt) + 12288, tid); }
#define DS_A(qi, Ab) { _Pragma("unroll") for(int i=0;i<4;++i){ \
      a[i][0] = *(const bf16x8*)&(Ab)[((qi)*64 + i*16 + lr)*64 + csw0]; \
      a[i][1] = *(const bf16x8*)&(Ab)[((qi)*64 + i*16 + lr)*64 + csw1]; } }
#define DS_B(qj, Bb) { _Pragma("unroll") for(int j=0;j<2;++j){ \
      bb[j][0] = *(const bf16x8*)&(Bb)[(bro + ((qj)*2+j)*16)*64 + csw0]; \
      bb[j][1] = *(const bf16x8*)&(Bb)[(bro + ((qj)*2+j)*16)*64 + csw1]; } }
#define MM(qi,qj) { __builtin_amdgcn_s_setprio(1); \
    _Pragma("unroll") for(int i=0;i<4;++i){ _Pragma("unroll") for(int j=0;j<2;++j){ \
      acc[(qi)*4+i][(qj)*2+j] = __builtin_amdgcn_mfma_f32_16x16x32_bf16(a[i][0], bb[j][0], acc[(qi)*4+i][(qj)*2+j],0,0,0); \
      acc[(qi)*4+i][(qj)*2+j] = __builtin_amdgcn_mfma_f32_16x16x32_bf16(a[i][1], bb[j][1], acc[(qi)*4+i][(qj)*2+j],0,0,0); } } \
    __builtin_amdgcn_s_setprio(0); }

// Mainloop body: 20 K-tiles, consumption-order staging S0..S3 (see r2 notes).
#define MAINLOOP_256(NKT) \
  ST_S0(0); ST_S1(0); ST_S2(0); ST_S3(0); \
  VMW(4); \
  BARX(); \
  for(int t = 0; t < (NKT)-1; ++t){ \
    const ushort_t* Ab = AB(t) + wr*8192; \
    const ushort_t* Bb = BB(t) + (wc>>1)*8192; \
    DS_A(0,Ab); DS_B(0,Bb); ST_S0(t+1); VMW(4); BARX(); MM(0,0); BARX(); \
    DS_B(1,Bb);             ST_S1(t+1); VMW(4); BARX(); MM(0,1); BARX(); \
    DS_A(1,Ab); DS_B(0,Bb); ST_S2(t+1);         BARX(); MM(1,0); BARX(); \
    DS_B(1,Bb);             ST_S3(t+1); VMW(4); BARX(); MM(1,1); BARX(); \
  } \
  { \
    const ushort_t* Ab = AB((NKT)-1) + wr*8192; \
    const ushort_t* Bb = BB((NKT)-1) + (wc>>1)*8192; \
    DS_A(0,Ab); DS_B(0,Bb); VMW(2); BARX(); MM(0,0); BARX(); \
    DS_B(1,Bb);             VMW(0); BARX(); MM(0,1); BARX(); \
    DS_A(1,Ab); DS_B(0,Bb);         BARX(); MM(1,0); BARX(); \
    DS_B(1,Bb);                             MM(1,1); \
  }

// ------------------------------------------- gemm1 + fused attention, 8p ---
// q = X @ Wq^T (256x256 tile, 8 waves); each wave's 128x64 sub-tile is one
// head -> per-wave epilogue with ZERO cross-wave traffic:
//   K:  direct global->B-fragment loads (kv is L2-resident)
//   q:  C->A transpose via 2KB dbuf LDS scratch per wave (XOR-swizzled)
//   P,V^T: per-wave LDS regions (stride 44/40, layouts proven in r0 kernel)
__global__ __launch_bounds__(512,2) void gemm1_attn_8p(
      const ushort_t* __restrict__ X, const ushort_t* __restrict__ Wq,
      const ushort_t* __restrict__ kv, const float* __restrict__ gates,
      ushort_t* __restrict__ Z){
  __shared__ __align__(16) ushort_t lds[65536];   // 128 KiB
  const int lid = (blockIdx.x & 7)*80 + (blockIdx.x >> 3);
  const int m0 = (lid/5)*256, n0 = (lid%5)*256;
  const int tid = threadIdx.x, l = tid & 63, w = tid >> 6;
  const int wr = w >> 2, wc = w & 3;
  const int lr = l & 15;
  const int csw0 = ((l>>4)*8)    ^ ((l&7)<<3);
  const int csw1 = (32+(l>>4)*8) ^ ((l&7)<<3);
  const int bro  = (wc & 1)*64 + lr;
  const ushort_t* Asrc = X  + (size_t)m0*D_;
  const ushort_t* Bsrc = Wq + (size_t)n0*D_;
  const f32x4 fz = {0.f,0.f,0.f,0.f};
  f32x4 acc[8][4];
  #pragma unroll
  for(int i=0;i<8;++i){
    #pragma unroll
    for(int j=0;j<4;++j) acc[i][j] = fz;
  }
  bf16x8 a[4][2], bb[2][2];

  MAINLOOP_256(20)

  BARX();                                   // all tile-19 ds_reads done before reuse
  // ---- epilogue: per-wave attention over 16 anat + 16 dis keys ------------
  const int b = m0 >> 10;
  const float gA = gates[b*2+0], gD = gates[b*2+1];
  ushort_t* R = lds + w*8192;               // per-wave 16 KB region
  // K B-fragments straight from global: lane = token lr, dims (l>>4)*8
  const ushort_t* kbase = kv + ((size_t)b*NTOK + lr)*D_ + n0 + wc*64 + (l>>4)*8;
  bf16x8 kA0 = *(const bf16x8*)(kbase);
  bf16x8 kA1 = *(const bf16x8*)(kbase + 32);
  bf16x8 kD0 = *(const bf16x8*)(kbase + (size_t)2*B_*NTOK*D_);
  bf16x8 kD1 = *(const bf16x8*)(kbase + (size_t)2*B_*NTOK*D_ + 32);
  // QK^T: 8 chunks of 16 rows; q C->A transpose through 2x1KB LDS scratch
  f32x4 scA[8], scD[8];
  #pragma unroll
  for(int i=0;i<8;++i){ scA[i] = fz; scD[i] = fz; }
  #pragma unroll
  for(int i=0;i<8;++i){
    ushort_t* qs = R + (i&1)*1024;
    #pragma unroll
    for(int j=0;j<4;++j){
      #pragma unroll
      for(int r=0;r<4;++r){
        int row = (l>>4)*4 + r;            // row within 16-chunk
        int col = j*16 + lr;               // dim within head
        qs[row*64 + ((((col>>3) ^ (row&7))<<3) | (col&7))] = f2b(acc[i][j][r]);
      }
    }
    LGKM0();                               // cross-lane RAW: writes visible
    bf16x8 af0 = *(const bf16x8*)&qs[lr*64 + ((((l>>4))   ^ (lr&7))<<3)];
    bf16x8 af1 = *(const bf16x8*)&qs[lr*64 + (((4+(l>>4)) ^ (lr&7))<<3)];
    scA[i] = __builtin_amdgcn_mfma_f32_16x16x32_bf16(af0, kA0, scA[i], 0,0,0);
    scA[i] = __builtin_amdgcn_mfma_f32_16x16x32_bf16(af1, kA1, scA[i], 0,0,0);
    scD[i] = __builtin_amdgcn_mfma_f32_16x16x32_bf16(af0, kD0, scD[i], 0,0,0);
    scD[i] = __builtin_amdgcn_mfma_f32_16x16x32_bf16(af1, kD1, scD[i], 0,0,0);
  }
  // V loads issued now (acc regs free); latency hides under softmax VALU
  uint4 vld[4];
  #pragma unroll
  for(int it=0; it<4; ++it){
    int u = it*64 + l;
    int tp = u >> 3, c = u & 7;
    int tensor = (tp < 16) ? 1 : 3;
    int t = tp & 15;
    vld[it] = *(const uint4*)(kv + (((size_t)tensor*B_ + b)*NTOK + t)*D_
                                 + n0 + wc*64 + c*8);
  }
  // softmax over 16 keys (t = lane&15), per tensor, gated; P -> LDS (stride 44)
  LGKM0();                                  // last q-scratch reads done (WAR vs ps)
  #pragma unroll
  for(int i=0;i<8;++i){
    #pragma unroll
    for(int r=0;r<4;++r){
      float vA = scA[i][r]*SCALE_, vD = scD[i][r]*SCALE_;
      float mA = vA, mD = vD;
      #pragma unroll
      for(int off=1; off<16; off<<=1){
        mA = fmaxf(mA, __shfl_xor(mA, off));
        mD = fmaxf(mD, __shfl_xor(mD, off));
      }
      float eA = __expf(vA - mA), eD = __expf(vD - mD);
      float sA = eA, sD = eD;
      #pragma unroll
      for(int off=1; off<16; off<<=1){
        sA += __shfl_xor(sA, off);
        sD += __shfl_xor(sD, off);
      }
      int lrow = i*16 + (l>>4)*4 + r;
      R[lrow*44 + lr]      = f2b(gA*eA/sA);
      R[lrow*44 + 16 + lr] = f2b(gD*eD/sD);
    }
  }
  // scatter V^T: vts[d][t'] at R+5632, stride 40
  ushort_t* vts = R + 5632;
  #pragma unroll
  for(int it=0; it<4; ++it){
    int u = it*64 + l;
    int tp = u >> 3, c = u & 7;
    const ushort_t* pv = (const ushort_t*)&vld[it];
    #pragma unroll
    for(int e=0;e<8;++e) vts[(c*8+e)*40 + tp] = pv[e];
  }
  LGKM0();                                  // ps + vts visible across lanes
  // PV: P(128x32) @ V^T -> z, K=32 one MFMA per (i,j)
  bf16x8 pa[8], vb[4];
  #pragma unroll
  for(int i=0;i<8;++i) pa[i] = *(const bf16x8*)&R[(i*16+lr)*44 + (l>>4)*8];
  #pragma unroll
  for(int j=0;j<4;++j)  vb[j] = *(const bf16x8*)&vts[(j*16+lr)*40 + (l>>4)*8];
  f32x4 z[8][4];
  #pragma unroll
  for(int i=0;i<8;++i){
    #pragma unroll
    for(int j=0;j<4;++j)
      z[i][j] = __builtin_amdgcn_mfma_f32_16x16x32_bf16(pa[i], vb[j], fz, 0,0,0);
  }
  #pragma unroll
  for(int i=0;i<8;++i){
    #pragma unroll
    for(int j=0;j<4;++j){
      #pragma unroll
      for(int r=0;r<4;++r){
        int row = m0 + wr*128 + i*16 + (l>>4)*4 + r;
        int col = n0 + wc*64 + j*16 + lr;
        Z[(size_t)row*D_ + col] = f2b(z[i][j][r]);
      }
    }
  }
}

// ----------------------------------------------- gemm2: out-proj, 8-phase --
__global__ __launch_bounds__(512,2) void gemm2_8p(
      const ushort_t* __restrict__ Zin, const ushort_t* __restrict__ Wo,
      const float* __restrict__ bias, const float* __restrict__ resid,
      float* __restrict__ out){
  __shared__ __align__(16) ushort_t lds[65536];   // A[2][2][128][64] | B same
  const int lid = (blockIdx.x & 7)*80 + (blockIdx.x >> 3);
  const int m0 = (lid/5)*256, n0 = (lid%5)*256;
  const int tid = threadIdx.x, l = tid & 63, w = tid >> 6;
  const int wr = w >> 2, wc = w & 3;
  const int lr = l & 15;
  const int csw0 = ((l>>4)*8)    ^ ((l&7)<<3);
  const int csw1 = (32+(l>>4)*8) ^ ((l&7)<<3);
  const int bro  = (wc & 1)*64 + lr;
  const ushort_t* Asrc = Zin + (size_t)m0*D_;
  const ushort_t* Bsrc = Wo  + (size_t)n0*D_;
  const f32x4 fz = {0.f,0.f,0.f,0.f};
  f32x4 acc[8][4];
  #pragma unroll
  for(int i=0;i<8;++i){
    #pragma unroll
    for(int j=0;j<4;++j) acc[i][j] = fz;
  }
  bf16x8 a[4][2], bb[2][2];

  MAINLOOP_256(20)

  // epilogue: bias + residual, f32 out
  float bj[4];
  #pragma unroll
  for(int j=0;j<4;++j) bj[j] = bias[n0 + wc*64 + j*16 + lr];
  #pragma unroll
  for(int i=0;i<8;++i){
    #pragma unroll
    for(int j=0;j<4;++j){
      #pragma unroll
      for(int r=0;r<4;++r){
        int m = m0 + wr*128 + i*16 + (l>>4)*4 + r;
        int n = n0 + wc*64 + j*16 + lr;
        out[(size_t)m*D_ + n] = acc[i][j][r] + bj[j] + resid[(size_t)m*D_ + n];
      }
    }
  }
}

// --------------------------------------------------------------------------
extern "C" void kernel_launch(void* const* d_in, const int* in_sizes, int n_in,
                              void* d_out, int out_size, void* d_ws, size_t ws_size,
                              hipStream_t stream){
  const float* hidden = (const float*)d_in[0];
  const float* enc    = (const float*)d_in[1];
  const float* w_q    = (const float*)d_in[2];
  const float* w_k    = (const float*)d_in[3];
  const float* w_v    = (const float*)d_in[4];
  const float* w_kd   = (const float*)d_in[5];
  const float* w_vd   = (const float*)d_in[6];
  const float* w_gate = (const float*)d_in[7];
  const float* b_gate = (const float*)d_in[8];
  const float* aLog   = (const float*)d_in[9];
  const float* dLog   = (const float*)d_in[10];
  const float* w_out  = (const float*)d_in[11];
  const float* b_out  = (const float*)d_in[12];
  float* out = (float*)d_out;

  char* ws = (char*)d_ws;
  ushort_t* z_bf   = (ushort_t*)(ws + 0);           // 83,886,080 B
  ushort_t* kv_bf  = (ushort_t*)(ws + 83886080);    //  5,242,880 B
  ushort_t* wq_bf  = (ushort_t*)(ws + 89128960);    //  3,276,800 B
  ushort_t* wk_bf  = (ushort_t*)(ws + 92405760);    //  1,966,080 B
  ushort_t* wv_bf  = (ushort_t*)(ws + 94371840);    //  1,966,080 B
  ushort_t* wkd_bf = (ushort_t*)(ws + 96337920);    //  1,966,080 B
  ushort_t* wvd_bf = (ushort_t*)(ws + 98304000);    //  1,966,080 B
  ushort_t* wo_bf  = (ushort_t*)(ws + 100270080);   //  3,276,800 B
  ushort_t* enc_bf = (ushort_t*)(ws + 103546880);   //  2,359,296 B
  float*    gates  = (float*)   (ws + 105906176);   //        256 B

  // hidden bf16 lives in the FIRST HALF OF d_out (168 MB f32 buffer; gemm1
  // consumes it fully before gemm2 writes d_out — stream-ordered, safe).
  ushort_t* hid_bf = (ushort_t*)d_out;              // 83,886,080 B <= out bytes

  CvtArgs ca;
  ca.src[0]=w_q;   ca.dst[0]=wq_bf;  ca.n[0]=D_*D_;
  ca.src[1]=w_k;   ca.dst[1]=wk_bf;  ca.n[1]=D_*CROSS_;
  ca.src[2]=w_v;   ca.dst[2]=wv_bf;  ca.n[2]=D_*CROSS_;
  ca.src[3]=w_kd;  ca.dst[3]=wkd_bf; ca.n[3]=D_*CROSS_;
  ca.src[4]=w_vd;  ca.dst[4]=wvd_bf; ca.n[4]=D_*CROSS_;
  ca.src[5]=w_out; ca.dst[5]=wo_bf;  ca.n[5]=D_*D_;
  ca.src[6]=enc;   ca.dst[6]=enc_bf; ca.n[6]=B_*48*CROSS_;
  cvt_kernel<<<dim3(1600,7), 256, 0, stream>>>(ca);
  cvt_big<<<20480, 256, 0, stream>>>(hidden, hid_bf, B_*S_*D_);

  gates_kernel<<<32, 256, 0, stream>>>(enc, w_gate, b_gate, aLog, dLog, gates);
  kv_gemm<<<dim3(4,10,4), 256, 0, stream>>>(enc_bf, wk_bf, wv_bf, wkd_bf, wvd_bf, kv_bf);
  gemm1_attn_8p<<<640, 512, 0, stream>>>(hid_bf, wq_bf, kv_bf, gates, z_bf);
  gemm2_8p<<<640, 512, 0, stream>>>(z_bf, wo_bf, b_out, hidden, out);
}

// Round 5
// 656.621 us; speedup vs baseline: 1.1229x; 1.0149x over previous
//
#include <hip/hip_runtime.h>
#include <stdint.h>

#define B_     32
#define S_     1024
#define D_     1280
#define CROSS_ 768
#define NTOK   16
#define SCALE_ 0.125f

typedef __bf16 bf16x8 __attribute__((ext_vector_type(8)));
typedef float  f32x4  __attribute__((ext_vector_type(4)));
typedef unsigned short ushort_t;
typedef unsigned int   uint_t;

__device__ __forceinline__ float b2f(ushort_t h){ return __uint_as_float(((uint_t)h)<<16); }
__device__ __forceinline__ ushort_t f2b(float f){
  uint_t u = __float_as_uint(f);
  u += 0x7FFFu + ((u>>16)&1u);           // RNE
  return (ushort_t)(u>>16);
}
__device__ __forceinline__ uint_t pk2(float x, float y){
  return (uint_t)f2b(x) | ((uint_t)f2b(y)<<16);
}

__device__ __forceinline__ void gload_lds16(const void* g, void* l){
  __builtin_amdgcn_global_load_lds((const __attribute__((address_space(1))) void*)g,
                                   (__attribute__((address_space(3))) void*)l, 16, 0, 0);
}

// ------------------------------------------------------------ cvt f32->bf16
struct CvtArgs { const float* src[7]; ushort_t* dst[7]; int n[7]; };
__global__ void cvt_kernel(CvtArgs a){
  int t = blockIdx.y;
  const float* s = a.src[t]; ushort_t* d = a.dst[t]; int n = a.n[t];
  int i = (blockIdx.x*blockDim.x + threadIdx.x)*4;
  if(i >= n) return;
  float4 v = *(const float4*)(s+i);
  uint2 o; o.x = pk2(v.x,v.y); o.y = pk2(v.z,v.w);
  *(uint2*)(d+i) = o;
}

__global__ void cvt_big(const float* __restrict__ s, ushort_t* __restrict__ d, int n){
  int i = (blockIdx.x*blockDim.x + threadIdx.x)*8;
  if(i >= n) return;
  float4 v0 = *(const float4*)(s+i), v1 = *(const float4*)(s+i+4);
  uint4 o = { pk2(v0.x,v0.y), pk2(v0.z,v0.w), pk2(v1.x,v1.y), pk2(v1.z,v1.w) };
  *(uint4*)(d+i) = o;
}

// ---------------------------------------------------------------- gates ----
__global__ void gates_kernel(const float* __restrict__ enc,
                             const float* __restrict__ w_gate,
                             const float* __restrict__ b_gate,
                             const float* __restrict__ aLog,
                             const float* __restrict__ dLog,
                             float* __restrict__ gates){
  int b = blockIdx.x, tid = threadIdx.x;
  __shared__ float red[256];
  float acc = 0.f;
  for(int k = tid; k < CROSS_; k += 256){
    float s = 0.f;
    for(int t = 0; t < NTOK; ++t)
      s += enc[(size_t)(b*48 + t)*CROSS_ + k];       // dis tokens = enc[:, :16]
    acc += w_gate[k] * s;
  }
  red[tid] = acc; __syncthreads();
  for(int off = 128; off > 0; off >>= 1){
    if(tid < off) red[tid] += red[tid+off];
    __syncthreads();
  }
  if(tid == 0){
    float shift = red[0]*(1.f/16.f) + b_gate[0];
    gates[b*2+0] = 1.f/(1.f+__expf(shift - aLog[0]));     // sigmoid(aLog - shift)
    gates[b*2+1] = 1.f/(1.f+__expf(-(dLog[0] + shift)));  // sigmoid(dLog + shift)
  }
}

// --------------------------------------------------------------- kv gemm ---
// C[tau][b][t][n] = tokens(tau) @ W(tau)^T ; M=512 (b*16+t), N=1280, K=768
__global__ __launch_bounds__(256) void kv_gemm(const ushort_t* __restrict__ enc,
      const ushort_t* __restrict__ wk,  const ushort_t* __restrict__ wv,
      const ushort_t* __restrict__ wkd, const ushort_t* __restrict__ wvd,
      ushort_t* __restrict__ kv){
  __shared__ __align__(16) ushort_t As[128*64];
  __shared__ __align__(16) ushort_t Bs[128*64];
  const int tau = blockIdx.z;
  const ushort_t* W = (tau==0)? wk : (tau==1)? wv : (tau==2)? wkd : wvd;
  const int tok_off = (tau < 2) ? NTOK : 0;   // anat = enc[:,16:32], dis = enc[:,0:16]
  const int m0 = blockIdx.x*128, n0 = blockIdx.y*128;
  const int tid = threadIdx.x, l = tid & 63, w = tid >> 6;
  const int wm = (w&1)*64, wn = (w>>1)*64;
  const f32x4 fz = {0.f,0.f,0.f,0.f};
  f32x4 acc[4][4];
  #pragma unroll
  for(int i=0;i<4;++i){
    #pragma unroll
    for(int j=0;j<4;++j) acc[i][j] = fz;
  }
  for(int kt = 0; kt < CROSS_/64; ++kt){
    const int k0 = kt*64;
    #pragma unroll
    for(int i=0;i<4;++i){
      int row = (w*4+i)*8 + (l>>3);
      int c   = l & 7;
      int gm  = m0 + row;
      int er  = (gm>>4)*48 + tok_off + (gm&15);
      gload_lds16(enc + (size_t)er*CROSS_ + k0 + c*8, As + (w*4+i)*512);
      gload_lds16(W  + (size_t)(n0+row)*CROSS_ + k0 + c*8, Bs + (w*4+i)*512);
    }
    __syncthreads();
    #pragma unroll
    for(int ks = 0; ks < 64; ks += 32){
      bf16x8 a[4], bq[4];
      #pragma unroll
      for(int i=0;i<4;++i) a[i]  = *(const bf16x8*)&As[(wm+i*16+(l&15))*64 + ks + (l>>4)*8];
      #pragma unroll
      for(int j=0;j<4;++j) bq[j] = *(const bf16x8*)&Bs[(wn+j*16+(l&15))*64 + ks + (l>>4)*8];
      #pragma unroll
      for(int i=0;i<4;++i){
        #pragma unroll
        for(int j=0;j<4;++j)
          acc[i][j] = __builtin_amdgcn_mfma_f32_16x16x32_bf16(a[i], bq[j], acc[i][j], 0,0,0);
      }
    }
    __syncthreads();
  }
  #pragma unroll
  for(int i=0;i<4;++i){
    #pragma unroll
    for(int j=0;j<4;++j){
      #pragma unroll
      for(int r=0;r<4;++r){
        int m = m0 + wm + i*16 + (l>>4)*4 + r;
        int n = n0 + wn + j*16 + (l&15);
        int b = m >> 4, t = m & 15;
        kv[(((size_t)tau*B_ + b)*NTOK + t)*D_ + n] = f2b(acc[i][j][r]);
      }
    }
  }
}

// ---------------------------------------------------------------------------
// 256^2 mainloop, BK=64, 8 waves.  A triple-buffered, B double-buffered
// (LDS = 3*32K + 2*32K = 160 KB).  ISSUE ORDER MATCHES DEADLINE ORDER
// (round-4 lesson): per tile t issue GB0(t+1)@p0, GB1(t+1)@p1,
// GA0(t+2)@p2, GA1(t+2)@p3.  Steady FIFO queue entering tile t p0 =
// [GB1(t), GA0(t+1), GA1(t+1)] (6 loads).  VMW(6)@p0 retires GB1(t)
// (read at p1); VMW(6)@p3 retires GA0(t+1),GA1(t+1),GB0(t+1) (read from
// next p0).  A verified 4-5 phases after issue (covers ~900cy HBM);
// B 3 phases (L2-resident weights).  Tail drains 6 -> 2 -> 0.
#define VMW(n)  asm volatile("s_waitcnt vmcnt(" #n ")" ::: "memory")
#define FENCE() asm volatile("" ::: "memory")
#define BARX()  do{ FENCE(); __builtin_amdgcn_s_barrier(); FENCE(); }while(0)
#define LGKM0() asm volatile("s_waitcnt lgkmcnt(0)" ::: "memory")

// one 64x64 A quarter (8KB = 512thr x 16B): LDS linear, source col pre-XORed
__device__ __forceinline__ void stage_aq(const ushort_t* __restrict__ g,
                                         ushort_t* le, int tid){
  int row = tid >> 3;                       // 0..63 (region base is mult of 8)
  int c   = ((tid & 7) ^ (row & 7)) << 3;   // pre-swizzled col chunk
  gload_lds16(g + (size_t)row*D_ + c, le + (tid>>6)*512);
}
// two 32-row B slabs within one 128-row half: rows [s0,s0+32) and [s0+64,s0+96)
__device__ __forceinline__ void stage_b2(const ushort_t* __restrict__ g,
                                         ushort_t* lh, int s0, int tid){
  int w   = tid >> 6;
  int blk = w >> 2;                         // waves 0-3 -> slab s0, 4-7 -> s0+64
  int t   = tid & 255;
  int rr  = s0 + blk*64 + (t >> 3);         // row within half (mult-of-8 bases)
  int c   = ((t & 7) ^ (rr & 7)) << 3;
  gload_lds16(g + (size_t)rr*D_ + c, lh + (s0 + blk*64)*64 + (w&3)*512);
}

#define A3(s) (lds + (s)*16384)
#define B2(u) (lds + 49152 + (u)*16384)
#define ST_GA0(tt,s) { stage_aq(Asrc + (size_t)  0*D_ + (tt)*64, A3(s),          tid); \
                       stage_aq(Asrc + (size_t)128*D_ + (tt)*64, A3(s) + 8192,   tid); }
#define ST_GA1(tt,s) { stage_aq(Asrc + (size_t) 64*D_ + (tt)*64, A3(s) + 4096,   tid); \
                       stage_aq(Asrc + (size_t)192*D_ + (tt)*64, A3(s) + 12288,  tid); }
#define ST_GB0(tt,u) { stage_b2(Bsrc + (size_t)  0*D_ + (tt)*64, B2(u),        0, tid); \
                       stage_b2(Bsrc + (size_t)128*D_ + (tt)*64, B2(u) + 8192, 0, tid); }
#define ST_GB1(tt,u) { stage_b2(Bsrc + (size_t)  0*D_ + (tt)*64, B2(u),       32, tid); \
                       stage_b2(Bsrc + (size_t)128*D_ + (tt)*64, B2(u) + 8192,32, tid); }
#define DS_A(qi, Ab) { _Pragma("unroll") for(int i=0;i<4;++i){ \
      a[i][0] = *(const bf16x8*)&(Ab)[((qi)*64 + i*16 + lr)*64 + csw0]; \
      a[i][1] = *(const bf16x8*)&(Ab)[((qi)*64 + i*16 + lr)*64 + csw1]; } }
#define DS_B(qj, Bb) { _Pragma("unroll") for(int j=0;j<2;++j){ \
      bb[j][0] = *(const bf16x8*)&(Bb)[(bro + ((qj)*2+j)*16)*64 + csw0]; \
      bb[j][1] = *(const bf16x8*)&(Bb)[(bro + ((qj)*2+j)*16)*64 + csw1]; } }
#define MM(qi,qj) { __builtin_amdgcn_s_setprio(1); \
    _Pragma("unroll") for(int i=0;i<4;++i){ _Pragma("unroll") for(int j=0;j<2;++j){ \
      acc[(qi)*4+i][(qj)*2+j] = __builtin_amdgcn_mfma_f32_16x16x32_bf16(a[i][0], bb[j][0], acc[(qi)*4+i][(qj)*2+j],0,0,0); \
      acc[(qi)*4+i][(qj)*2+j] = __builtin_amdgcn_mfma_f32_16x16x32_bf16(a[i][1], bb[j][1], acc[(qi)*4+i][(qj)*2+j],0,0,0); } } \
    __builtin_amdgcn_s_setprio(0); }

// one steady K-tile; buffer indices compile-time.
#define TILE_N(t, s_cur, s_pf2, u_cur, u_nx) { \
    const ushort_t* Ab = A3(s_cur) + wr*8192; \
    const ushort_t* Bb = B2(u_cur) + (wc>>1)*8192; \
    DS_A(0,Ab); DS_B(0,Bb); ST_GB0((t)+1,u_nx); VMW(6); BARX(); MM(0,0); BARX(); \
    DS_B(1,Bb);             ST_GB1((t)+1,u_nx);         BARX(); MM(0,1); BARX(); \
    DS_A(1,Ab); DS_B(0,Bb); ST_GA0((t)+2,s_pf2);        BARX(); MM(1,0); BARX(); \
    DS_B(1,Bb);             ST_GA1((t)+2,s_pf2); VMW(6); BARX(); MM(1,1); BARX(); }

// 20 K-tiles: prologue issues (deadline order) GA0(0),GA1(0),GB0(0),GB1(0),
// GA0(1),GA1(1); VMW(6) verifies GA0(0),GA1(0),GB0(0).  Steady t=0..17
// (3 x unroll-6 so s=t%3, u=t&1 compile-time).  Tile 18 stages GB(19) only
// (VMW(6)@p0, VMW(2)@p3); tile 19 drains (VMW(0)@p0).
#define MAINLOOP4 \
  ST_GA0(0,0); ST_GA1(0,0); ST_GB0(0,0); ST_GB1(0,0); ST_GA0(1,1); ST_GA1(1,1); \
  VMW(6); \
  BARX(); \
  for(int tt6 = 0; tt6 < 18; tt6 += 6){ \
    _Pragma("unroll") \
    for(int uu = 0; uu < 6; ++uu){ \
      TILE_N(tt6+uu, (uu%3), ((uu+2)%3), (uu&1), ((uu+1)&1)); \
    } \
  } \
  { /* tile 18: s_cur=0, u_cur=0; stage GB(19) -> u=1 */ \
    const ushort_t* Ab = A3(0) + wr*8192; \
    const ushort_t* Bb = B2(0) + (wc>>1)*8192; \
    DS_A(0,Ab); DS_B(0,Bb); ST_GB0(19,1); VMW(6); BARX(); MM(0,0); BARX(); \
    DS_B(1,Bb);             ST_GB1(19,1);         BARX(); MM(0,1); BARX(); \
    DS_A(1,Ab); DS_B(0,Bb);                       BARX(); MM(1,0); BARX(); \
    DS_B(1,Bb);                           VMW(2); BARX(); MM(1,1); BARX(); \
  } \
  { /* tile 19: s_cur=1, u_cur=1; drain */ \
    const ushort_t* Ab = A3(1) + wr*8192; \
    const ushort_t* Bb = B2(1) + (wc>>1)*8192; \
    DS_A(0,Ab); DS_B(0,Bb); VMW(0); BARX(); MM(0,0); BARX(); \
    DS_B(1,Bb);                     BARX(); MM(0,1); BARX(); \
    DS_A(1,Ab); DS_B(0,Bb);         BARX(); MM(1,0); BARX(); \
    DS_B(1,Bb);                             MM(1,1); \
  }

// ------------------------------------------- gemm1 + fused attention, 8p ---
// q = X @ Wq^T (256x256 tile, 8 waves); each wave's 128x64 sub-tile is one
// head -> per-wave epilogue with ZERO cross-wave traffic.
__global__ __launch_bounds__(512,2) void gemm1_attn_8p(
      const ushort_t* __restrict__ X, const ushort_t* __restrict__ Wq,
      const ushort_t* __restrict__ kv, const float* __restrict__ gates,
      ushort_t* __restrict__ Z){
  __shared__ __align__(16) ushort_t lds[81920];   // 160 KiB: A x3 | B x2
  const int lid = (blockIdx.x & 7)*80 + (blockIdx.x >> 3);
  const int m0 = (lid/5)*256, n0 = (lid%5)*256;
  const int tid = threadIdx.x, l = tid & 63, w = tid >> 6;
  const int wr = w >> 2, wc = w & 3;
  const int lr = l & 15;
  const int csw0 = ((l>>4)*8)    ^ ((l&7)<<3);
  const int csw1 = (32+(l>>4)*8) ^ ((l&7)<<3);
  const int bro  = (wc & 1)*64 + lr;
  const ushort_t* Asrc = X  + (size_t)m0*D_;
  const ushort_t* Bsrc = Wq + (size_t)n0*D_;
  const f32x4 fz = {0.f,0.f,0.f,0.f};
  f32x4 acc[8][4];
  #pragma unroll
  for(int i=0;i<8;++i){
    #pragma unroll
    for(int j=0;j<4;++j) acc[i][j] = fz;
  }
  bf16x8 a[4][2], bb[2][2];

  MAINLOOP4

  BARX();                                   // all tile-19 ds_reads done before reuse
  // ---- epilogue: per-wave attention over 16 anat + 16 dis keys ------------
  const int b = m0 >> 10;
  const float gA = gates[b*2+0], gD = gates[b*2+1];
  ushort_t* R = lds + w*8192;               // per-wave 16 KB region
  // K B-fragments straight from global: lane = token lr, dims (l>>4)*8
  const ushort_t* kbase = kv + ((size_t)b*NTOK + lr)*D_ + n0 + wc*64 + (l>>4)*8;
  bf16x8 kA0 = *(const bf16x8*)(kbase);
  bf16x8 kA1 = *(const bf16x8*)(kbase + 32);
  bf16x8 kD0 = *(const bf16x8*)(kbase + (size_t)2*B_*NTOK*D_);
  bf16x8 kD1 = *(const bf16x8*)(kbase + (size_t)2*B_*NTOK*D_ + 32);
  // QK^T: 8 chunks of 16 rows; q C->A transpose through 2x1KB LDS scratch
  f32x4 scA[8], scD[8];
  #pragma unroll
  for(int i=0;i<8;++i){ scA[i] = fz; scD[i] = fz; }
  #pragma unroll
  for(int i=0;i<8;++i){
    ushort_t* qs = R + (i&1)*1024;
    #pragma unroll
    for(int j=0;j<4;++j){
      #pragma unroll
      for(int r=0;r<4;++r){
        int row = (l>>4)*4 + r;            // row within 16-chunk
        int col = j*16 + lr;               // dim within head
        qs[row*64 + ((((col>>3) ^ (row&7))<<3) | (col&7))] = f2b(acc[i][j][r]);
      }
    }
    LGKM0();                               // cross-lane RAW: writes visible
    bf16x8 af0 = *(const bf16x8*)&qs[lr*64 + ((((l>>4))   ^ (lr&7))<<3)];
    bf16x8 af1 = *(const bf16x8*)&qs[lr*64 + (((4+(l>>4)) ^ (lr&7))<<3)];
    scA[i] = __builtin_amdgcn_mfma_f32_16x16x32_bf16(af0, kA0, scA[i], 0,0,0);
    scA[i] = __builtin_amdgcn_mfma_f32_16x16x32_bf16(af1, kA1, scA[i], 0,0,0);
    scD[i] = __builtin_amdgcn_mfma_f32_16x16x32_bf16(af0, kD0, scD[i], 0,0,0);
    scD[i] = __builtin_amdgcn_mfma_f32_16x16x32_bf16(af1, kD1, scD[i], 0,0,0);
  }
  // V loads issued now (acc regs free); latency hides under softmax VALU
  uint4 vld[4];
  #pragma unroll
  for(int it=0; it<4; ++it){
    int u = it*64 + l;
    int tp = u >> 3, c = u & 7;
    int tensor = (tp < 16) ? 1 : 3;
    int t = tp & 15;
    vld[it] = *(const uint4*)(kv + (((size_t)tensor*B_ + b)*NTOK + t)*D_
                                 + n0 + wc*64 + c*8);
  }
  // softmax over 16 keys (t = lane&15), per tensor, gated; P -> LDS (stride 44)
  LGKM0();                                  // last q-scratch reads done (WAR vs ps)
  #pragma unroll
  for(int i=0;i<8;++i){
    #pragma unroll
    for(int r=0;r<4;++r){
      float vA = scA[i][r]*SCALE_, vD = scD[i][r]*SCALE_;
      float mA = vA, mD = vD;
      #pragma unroll
      for(int off=1; off<16; off<<=1){
        mA = fmaxf(mA, __shfl_xor(mA, off));
        mD = fmaxf(mD, __shfl_xor(mD, off));
      }
      float eA = __expf(vA - mA), eD = __expf(vD - mD);
      float sA = eA, sD = eD;
      #pragma unroll
      for(int off=1; off<16; off<<=1){
        sA += __shfl_xor(sA, off);
        sD += __shfl_xor(sD, off);
      }
      int lrow = i*16 + (l>>4)*4 + r;
      R[lrow*44 + lr]      = f2b(gA*eA/sA);
      R[lrow*44 + 16 + lr] = f2b(gD*eD/sD);
    }
  }
  // scatter V^T: vts[d][t'] at R+5632, stride 40
  ushort_t* vts = R + 5632;
  #pragma unroll
  for(int it=0; it<4; ++it){
    int u = it*64 + l;
    int tp = u >> 3, c = u & 7;
    const ushort_t* pv = (const ushort_t*)&vld[it];
    #pragma unroll
    for(int e=0;e<8;++e) vts[(c*8+e)*40 + tp] = pv[e];
  }
  LGKM0();                                  // ps + vts visible across lanes
  // PV: P(128x32) @ V^T -> z, K=32 one MFMA per (i,j)
  bf16x8 pa[8], vb[4];
  #pragma unroll
  for(int i=0;i<8;++i) pa[i] = *(const bf16x8*)&R[(i*16+lr)*44 + (l>>4)*8];
  #pragma unroll
  for(int j=0;j<4;++j)  vb[j] = *(const bf16x8*)&vts[(j*16+lr)*40 + (l>>4)*8];
  f32x4 z[8][4];
  #pragma unroll
  for(int i=0;i<8;++i){
    #pragma unroll
    for(int j=0;j<4;++j)
      z[i][j] = __builtin_amdgcn_mfma_f32_16x16x32_bf16(pa[i], vb[j], fz, 0,0,0);
  }
  #pragma unroll
  for(int i=0;i<8;++i){
    #pragma unroll
    for(int j=0;j<4;++j){
      #pragma unroll
      for(int r=0;r<4;++r){
        int row = m0 + wr*128 + i*16 + (l>>4)*4 + r;
        int col = n0 + wc*64 + j*16 + lr;
        Z[(size_t)row*D_ + col] = f2b(z[i][j][r]);
      }
    }
  }
}

// ----------------------------------------------- gemm2: out-proj, 8-phase --
__global__ __launch_bounds__(512,2) void gemm2_8p(
      const ushort_t* __restrict__ Zin, const ushort_t* __restrict__ Wo,
      const float* __restrict__ bias, const float* __restrict__ resid,
      float* __restrict__ out){
  __shared__ __align__(16) ushort_t lds[81920];   // 160 KiB: A x3 | B x2
  const int lid = (blockIdx.x & 7)*80 + (blockIdx.x >> 3);
  const int m0 = (lid/5)*256, n0 = (lid%5)*256;
  const int tid = threadIdx.x, l = tid & 63, w = tid >> 6;
  const int wr = w >> 2, wc = w & 3;
  const int lr = l & 15;
  const int csw0 = ((l>>4)*8)    ^ ((l&7)<<3);
  const int csw1 = (32+(l>>4)*8) ^ ((l&7)<<3);
  const int bro  = (wc & 1)*64 + lr;
  const ushort_t* Asrc = Zin + (size_t)m0*D_;
  const ushort_t* Bsrc = Wo  + (size_t)n0*D_;
  const f32x4 fz = {0.f,0.f,0.f,0.f};
  f32x4 acc[8][4];
  #pragma unroll
  for(int i=0;i<8;++i){
    #pragma unroll
    for(int j=0;j<4;++j) acc[i][j] = fz;
  }
  bf16x8 a[4][2], bb[2][2];

  MAINLOOP4

  // epilogue: bias + residual, f32 out
  float bj[4];
  #pragma unroll
  for(int j=0;j<4;++j) bj[j] = bias[n0 + wc*64 + j*16 + lr];
  #pragma unroll
  for(int i=0;i<8;++i){
    #pragma unroll
    for(int j=0;j<4;++j){
      #pragma unroll
      for(int r=0;r<4;++r){
        int m = m0 + wr*128 + i*16 + (l>>4)*4 + r;
        int n = n0 + wc*64 + j*16 + lr;
        out[(size_t)m*D_ + n] = acc[i][j][r] + bj[j] + resid[(size_t)m*D_ + n];
      }
    }
  }
}

// --------------------------------------------------------------------------
extern "C" void kernel_launch(void* const* d_in, const int* in_sizes, int n_in,
                              void* d_out, int out_size, void* d_ws, size_t ws_size,
                              hipStream_t stream){
  const float* hidden = (const float*)d_in[0];
  const float* enc    = (const float*)d_in[1];
  const float* w_q    = (const float*)d_in[2];
  const float* w_k    = (const float*)d_in[3];
  const float* w_v    = (const float*)d_in[4];
  const float* w_kd   = (const float*)d_in[5];
  const float* w_vd   = (const float*)d_in[6];
  const float* w_gate = (const float*)d_in[7];
  const float* b_gate = (const float*)d_in[8];
  const float* aLog   = (const float*)d_in[9];
  const float* dLog   = (const float*)d_in[10];
  const float* w_out  = (const float*)d_in[11];
  const float* b_out  = (const float*)d_in[12];
  float* out = (float*)d_out;

  char* ws = (char*)d_ws;
  ushort_t* z_bf   = (ushort_t*)(ws + 0);           // 83,886,080 B
  ushort_t* kv_bf  = (ushort_t*)(ws + 83886080);    //  5,242,880 B
  ushort_t* wq_bf  = (ushort_t*)(ws + 89128960);    //  3,276,800 B
  ushort_t* wk_bf  = (ushort_t*)(ws + 92405760);    //  1,966,080 B
  ushort_t* wv_bf  = (ushort_t*)(ws + 94371840);    //  1,966,080 B
  ushort_t* wkd_bf = (ushort_t*)(ws + 96337920);    //  1,966,080 B
  ushort_t* wvd_bf = (ushort_t*)(ws + 98304000);    //  1,966,080 B
  ushort_t* wo_bf  = (ushort_t*)(ws + 100270080);   //  3,276,800 B
  ushort_t* enc_bf = (ushort_t*)(ws + 103546880);   //  2,359,296 B
  float*    gates  = (float*)   (ws + 105906176);   //        256 B

  // hidden bf16 lives in the FIRST HALF OF d_out (168 MB f32 buffer; gemm1
  // consumes it fully before gemm2 writes d_out — stream-ordered, safe).
  ushort_t* hid_bf = (ushort_t*)d_out;              // 83,886,080 B <= out bytes

  CvtArgs ca;
  ca.src[0]=w_q;   ca.dst[0]=wq_bf;  ca.n[0]=D_*D_;
  ca.src[1]=w_k;   ca.dst[1]=wk_bf;  ca.n[1]=D_*CROSS_;
  ca.src[2]=w_v;   ca.dst[2]=wv_bf;  ca.n[2]=D_*CROSS_;
  ca.src[3]=w_kd;  ca.dst[3]=wkd_bf; ca.n[3]=D_*CROSS_;
  ca.src[4]=w_vd;  ca.dst[4]=wvd_bf; ca.n[4]=D_*CROSS_;
  ca.src[5]=w_out; ca.dst[5]=wo_bf;  ca.n[5]=D_*D_;
  ca.src[6]=enc;   ca.dst[6]=enc_bf; ca.n[6]=B_*48*CROSS_;
  cvt_kernel<<<dim3(1600,7), 256, 0, stream>>>(ca);
  cvt_big<<<20480, 256, 0, stream>>>(hidden, hid_bf, B_*S_*D_);

  gates_kernel<<<32, 256, 0, stream>>>(enc, w_gate, b_gate, aLog, dLog, gates);
  kv_gemm<<<dim3(4,10,4), 256, 0, stream>>>(enc_bf, wk_bf, wv_bf, wkd_bf, wvd_bf, kv_bf);
  gemm1_attn_8p<<<640, 512, 0, stream>>>(hid_bf, wq_bf, kv_bf, gates, z_bf);
  gemm2_8p<<<640, 512, 0, stream>>>(z_bf, wo_bf, b_out, hidden, out);
}

// Round 6
// 649.016 us; speedup vs baseline: 1.1360x; 1.0117x over previous
//
#include <hip/hip_runtime.h>
#include <stdint.h>

#define B_     32
#define S_     1024
#define D_     1280
#define CROSS_ 768
#define NTOK   16
#define SCALE_ 0.125f

typedef __bf16 bf16x8 __attribute__((ext_vector_type(8)));
typedef float  f32x4  __attribute__((ext_vector_type(4)));
typedef unsigned short ushort_t;
typedef unsigned int   uint_t;

__device__ __forceinline__ float b2f(ushort_t h){ return __uint_as_float(((uint_t)h)<<16); }
__device__ __forceinline__ ushort_t f2b(float f){
  uint_t u = __float_as_uint(f);
  u += 0x7FFFu + ((u>>16)&1u);           // RNE
  return (ushort_t)(u>>16);
}
__device__ __forceinline__ uint_t pk2(float x, float y){
  return (uint_t)f2b(x) | ((uint_t)f2b(y)<<16);
}

__device__ __forceinline__ void gload_lds16(const void* g, void* l){
  __builtin_amdgcn_global_load_lds((const __attribute__((address_space(1))) void*)g,
                                   (__attribute__((address_space(3))) void*)l, 16, 0, 0);
}

// ------------------------------------------------------------ cvt f32->bf16
struct CvtArgs { const float* src[7]; ushort_t* dst[7]; int n[7]; };
__global__ void cvt_kernel(CvtArgs a){
  int t = blockIdx.y;
  const float* s = a.src[t]; ushort_t* d = a.dst[t]; int n = a.n[t];
  int i = (blockIdx.x*blockDim.x + threadIdx.x)*4;
  if(i >= n) return;
  float4 v = *(const float4*)(s+i);
  uint2 o; o.x = pk2(v.x,v.y); o.y = pk2(v.z,v.w);
  *(uint2*)(d+i) = o;
}

__global__ void cvt_big(const float* __restrict__ s, ushort_t* __restrict__ d, int n){
  int i = (blockIdx.x*blockDim.x + threadIdx.x)*8;
  if(i >= n) return;
  float4 v0 = *(const float4*)(s+i), v1 = *(const float4*)(s+i+4);
  uint4 o = { pk2(v0.x,v0.y), pk2(v0.z,v0.w), pk2(v1.x,v1.y), pk2(v1.z,v1.w) };
  *(uint4*)(d+i) = o;
}

// ---------------------------------------------------------------- gates ----
__global__ void gates_kernel(const float* __restrict__ enc,
                             const float* __restrict__ w_gate,
                             const float* __restrict__ b_gate,
                             const float* __restrict__ aLog,
                             const float* __restrict__ dLog,
                             float* __restrict__ gates){
  int b = blockIdx.x, tid = threadIdx.x;
  __shared__ float red[256];
  float acc = 0.f;
  for(int k = tid; k < CROSS_; k += 256){
    float s = 0.f;
    for(int t = 0; t < NTOK; ++t)
      s += enc[(size_t)(b*48 + t)*CROSS_ + k];       // dis tokens = enc[:, :16]
    acc += w_gate[k] * s;
  }
  red[tid] = acc; __syncthreads();
  for(int off = 128; off > 0; off >>= 1){
    if(tid < off) red[tid] += red[tid+off];
    __syncthreads();
  }
  if(tid == 0){
    float shift = red[0]*(1.f/16.f) + b_gate[0];
    gates[b*2+0] = 1.f/(1.f+__expf(shift - aLog[0]));     // sigmoid(aLog - shift)
    gates[b*2+1] = 1.f/(1.f+__expf(-(dLog[0] + shift)));  // sigmoid(dLog + shift)
  }
}

// --------------------------------------------------------------- kv gemm ---
// C[tau][b][t][n] = tokens(tau) @ W(tau)^T ; M=512 (b*16+t), N=1280, K=768
__global__ __launch_bounds__(256) void kv_gemm(const ushort_t* __restrict__ enc,
      const ushort_t* __restrict__ wk,  const ushort_t* __restrict__ wv,
      const ushort_t* __restrict__ wkd, const ushort_t* __restrict__ wvd,
      ushort_t* __restrict__ kv){
  __shared__ __align__(16) ushort_t As[128*64];
  __shared__ __align__(16) ushort_t Bs[128*64];
  const int tau = blockIdx.z;
  const ushort_t* W = (tau==0)? wk : (tau==1)? wv : (tau==2)? wkd : wvd;
  const int tok_off = (tau < 2) ? NTOK : 0;   // anat = enc[:,16:32], dis = enc[:,0:16]
  const int m0 = blockIdx.x*128, n0 = blockIdx.y*128;
  const int tid = threadIdx.x, l = tid & 63, w = tid >> 6;
  const int wm = (w&1)*64, wn = (w>>1)*64;
  const f32x4 fz = {0.f,0.f,0.f,0.f};
  f32x4 acc[4][4];
  #pragma unroll
  for(int i=0;i<4;++i){
    #pragma unroll
    for(int j=0;j<4;++j) acc[i][j] = fz;
  }
  for(int kt = 0; kt < CROSS_/64; ++kt){
    const int k0 = kt*64;
    #pragma unroll
    for(int i=0;i<4;++i){
      int row = (w*4+i)*8 + (l>>3);
      int c   = l & 7;
      int gm  = m0 + row;
      int er  = (gm>>4)*48 + tok_off + (gm&15);
      gload_lds16(enc + (size_t)er*CROSS_ + k0 + c*8, As + (w*4+i)*512);
      gload_lds16(W  + (size_t)(n0+row)*CROSS_ + k0 + c*8, Bs + (w*4+i)*512);
    }
    __syncthreads();
    #pragma unroll
    for(int ks = 0; ks < 64; ks += 32){
      bf16x8 a[4], bq[4];
      #pragma unroll
      for(int i=0;i<4;++i) a[i]  = *(const bf16x8*)&As[(wm+i*16+(l&15))*64 + ks + (l>>4)*8];
      #pragma unroll
      for(int j=0;j<4;++j) bq[j] = *(const bf16x8*)&Bs[(wn+j*16+(l&15))*64 + ks + (l>>4)*8];
      #pragma unroll
      for(int i=0;i<4;++i){
        #pragma unroll
        for(int j=0;j<4;++j)
          acc[i][j] = __builtin_amdgcn_mfma_f32_16x16x32_bf16(a[i], bq[j], acc[i][j], 0,0,0);
      }
    }
    __syncthreads();
  }
  #pragma unroll
  for(int i=0;i<4;++i){
    #pragma unroll
    for(int j=0;j<4;++j){
      #pragma unroll
      for(int r=0;r<4;++r){
        int m = m0 + wm + i*16 + (l>>4)*4 + r;
        int n = n0 + wn + j*16 + (l&15);
        int b = m >> 4, t = m & 15;
        kv[(((size_t)tau*B_ + b)*NTOK + t)*D_ + n] = f2b(acc[i][j][r]);
      }
    }
  }
}

// ---------------------------------------------------------------------------
// 256^2 mainloop, BK=64, 8 waves.  Round-6 restructure: 2 phases / 2 barriers
// / 1 vmcnt per K-tile; B-subtile held in registers (bball) so LDS reads are
// 24 b128/wave/tile (was 32).  A triple-buffered, B double-buffered
// (LDS = 3*32K + 2*32K = 160 KB).
//   p0: {DS_BALL(8)+DS_A(0)(8); issue GB(t+1)x4; MM2(0)=32 MFMA; BARX}
//   p1: {DS_A(1)(8); issue GA(t+2)x4; MM2(1); VMW(4); BARX}
// FIFO (4-load groups): entering p0 outstanding=[GA(t+1)]; after p1 issue =
// [GA(t+1),GB(t+1),GA(t+2)] -> VMW(4) retires GA(t+1)+GB(t+1); both are read
// only after the following barrier (per-wave VMW -> barrier -> collective
// visibility).  A verified 4 phases after issue (HBM ~900cy covered); B 1
// phase (~1000cy, L2).  WAR: every region's last read completes before its
// wave's MM (lgkmcnt) and >=1 phase-end barrier precedes the re-stage issue.
#define VMW(n)  asm volatile("s_waitcnt vmcnt(" #n ")" ::: "memory")
#define FENCE() asm volatile("" ::: "memory")
#define BARX()  do{ FENCE(); __builtin_amdgcn_s_barrier(); FENCE(); }while(0)
#define LGKM0() asm volatile("s_waitcnt lgkmcnt(0)" ::: "memory")

// one 64x64 A quarter (8KB = 512thr x 16B): LDS linear, source col pre-XORed
__device__ __forceinline__ void stage_aq(const ushort_t* __restrict__ g,
                                         ushort_t* le, int tid){
  int row = tid >> 3;                       // 0..63 (region base is mult of 8)
  int c   = ((tid & 7) ^ (row & 7)) << 3;   // pre-swizzled col chunk
  gload_lds16(g + (size_t)row*D_ + c, le + (tid>>6)*512);
}
// two 32-row B slabs within one 128-row half: rows [s0,s0+32) and [s0+64,s0+96)
__device__ __forceinline__ void stage_b2(const ushort_t* __restrict__ g,
                                         ushort_t* lh, int s0, int tid){
  int w   = tid >> 6;
  int blk = w >> 2;                         // waves 0-3 -> slab s0, 4-7 -> s0+64
  int t   = tid & 255;
  int rr  = s0 + blk*64 + (t >> 3);         // row within half (mult-of-8 bases)
  int c   = ((t & 7) ^ (rr & 7)) << 3;
  gload_lds16(g + (size_t)rr*D_ + c, lh + (s0 + blk*64)*64 + (w&3)*512);
}

#define A3(s) (lds + (s)*16384)
#define B2(u) (lds + 49152 + (u)*16384)
#define ST_GA0(tt,s) { stage_aq(Asrc + (size_t)  0*D_ + (tt)*64, A3(s),          tid); \
                       stage_aq(Asrc + (size_t)128*D_ + (tt)*64, A3(s) + 8192,   tid); }
#define ST_GA1(tt,s) { stage_aq(Asrc + (size_t) 64*D_ + (tt)*64, A3(s) + 4096,   tid); \
                       stage_aq(Asrc + (size_t)192*D_ + (tt)*64, A3(s) + 12288,  tid); }
#define ST_GB0(tt,u) { stage_b2(Bsrc + (size_t)  0*D_ + (tt)*64, B2(u),        0, tid); \
                       stage_b2(Bsrc + (size_t)128*D_ + (tt)*64, B2(u) + 8192, 0, tid); }
#define ST_GB1(tt,u) { stage_b2(Bsrc + (size_t)  0*D_ + (tt)*64, B2(u),       32, tid); \
                       stage_b2(Bsrc + (size_t)128*D_ + (tt)*64, B2(u) + 8192,32, tid); }
#define DS_A(qi, Ab) { _Pragma("unroll") for(int i=0;i<4;++i){ \
      a[i][0] = *(const bf16x8*)&(Ab)[((qi)*64 + i*16 + lr)*64 + csw0]; \
      a[i][1] = *(const bf16x8*)&(Ab)[((qi)*64 + i*16 + lr)*64 + csw1]; } }
#define DS_BALL(Bb) { _Pragma("unroll") for(int jj=0;jj<4;++jj){ \
      bball[jj][0] = *(const bf16x8*)&(Bb)[(bro + jj*16)*64 + csw0]; \
      bball[jj][1] = *(const bf16x8*)&(Bb)[(bro + jj*16)*64 + csw1]; } }
#define MM2(qi) { __builtin_amdgcn_s_setprio(1); \
    _Pragma("unroll") for(int i=0;i<4;++i){ _Pragma("unroll") for(int jj=0;jj<4;++jj){ \
      acc[(qi)*4+i][jj] = __builtin_amdgcn_mfma_f32_16x16x32_bf16(a[i][0], bball[jj][0], acc[(qi)*4+i][jj],0,0,0); \
      acc[(qi)*4+i][jj] = __builtin_amdgcn_mfma_f32_16x16x32_bf16(a[i][1], bball[jj][1], acc[(qi)*4+i][jj],0,0,0); } } \
    __builtin_amdgcn_s_setprio(0); }

// one steady K-tile; buffer indices compile-time.
#define TILE_T(t, s_cur, s_pf2, u_cur, u_nx) { \
    const ushort_t* Ab = A3(s_cur) + wr*8192; \
    const ushort_t* Bb = B2(u_cur) + (wc>>1)*8192; \
    DS_BALL(Bb); DS_A(0,Ab); ST_GB0((t)+1,u_nx); ST_GB1((t)+1,u_nx); \
    MM2(0); BARX(); \
    DS_A(1,Ab); ST_GA0((t)+2,s_pf2); ST_GA1((t)+2,s_pf2); \
    MM2(1); VMW(4); BARX(); }

// 20 K-tiles: prologue issues GB(0),GA(0) [deadline t0] then GA(1); VMW(4)
// retires GB(0)+GA(0).  Steady t=0..17 (3 x unroll-6 so s=t%3, u=t&1 are
// compile-time).  Tile 18 stages GB(19) only, drains with VMW(0); tile 19
// is barrier-free (nothing staged, everything verified).
#define MAINLOOP5 \
  ST_GB0(0,0); ST_GB1(0,0); ST_GA0(0,0); ST_GA1(0,0); ST_GA0(1,1); ST_GA1(1,1); \
  VMW(4); \
  BARX(); \
  for(int tt6 = 0; tt6 < 18; tt6 += 6){ \
    _Pragma("unroll") \
    for(int uu = 0; uu < 6; ++uu){ \
      TILE_T(tt6+uu, (uu%3), ((uu+2)%3), (uu&1), ((uu+1)&1)); \
    } \
  } \
  { /* tile 18: s_cur=0, u_cur=0; stage GB(19) -> u=1; drain */ \
    const ushort_t* Ab = A3(0) + wr*8192; \
    const ushort_t* Bb = B2(0) + (wc>>1)*8192; \
    DS_BALL(Bb); DS_A(0,Ab); ST_GB0(19,1); ST_GB1(19,1); \
    MM2(0); BARX(); \
    DS_A(1,Ab); \
    MM2(1); VMW(0); BARX(); \
  } \
  { /* tile 19: s_cur=1, u_cur=1; no staging, no barriers */ \
    const ushort_t* Ab = A3(1) + wr*8192; \
    const ushort_t* Bb = B2(1) + (wc>>1)*8192; \
    DS_BALL(Bb); DS_A(0,Ab); MM2(0); \
    DS_A(1,Ab);              MM2(1); \
  }

// ------------------------------------------- gemm1 + fused attention -------
// q = X @ Wq^T (256x256 tile, 8 waves); each wave's 128x64 sub-tile is one
// head -> per-wave epilogue with ZERO cross-wave traffic.
__global__ __launch_bounds__(512,2) void gemm1_attn_8p(
      const ushort_t* __restrict__ X, const ushort_t* __restrict__ Wq,
      const ushort_t* __restrict__ kv, const float* __restrict__ gates,
      ushort_t* __restrict__ Z){
  __shared__ __align__(16) ushort_t lds[81920];   // 160 KiB: A x3 | B x2
  const int lid = (blockIdx.x & 7)*80 + (blockIdx.x >> 3);
  const int m0 = (lid/5)*256, n0 = (lid%5)*256;
  const int tid = threadIdx.x, l = tid & 63, w = tid >> 6;
  const int wr = w >> 2, wc = w & 3;
  const int lr = l & 15;
  const int csw0 = ((l>>4)*8)    ^ ((l&7)<<3);
  const int csw1 = (32+(l>>4)*8) ^ ((l&7)<<3);
  const int bro  = (wc & 1)*64 + lr;
  const ushort_t* Asrc = X  + (size_t)m0*D_;
  const ushort_t* Bsrc = Wq + (size_t)n0*D_;
  const f32x4 fz = {0.f,0.f,0.f,0.f};
  f32x4 acc[8][4];
  #pragma unroll
  for(int i=0;i<8;++i){
    #pragma unroll
    for(int j=0;j<4;++j) acc[i][j] = fz;
  }
  bf16x8 a[4][2], bball[4][2];

  MAINLOOP5

  BARX();                                   // all tile-19 ds_reads done before reuse
  // ---- epilogue: per-wave attention over 16 anat + 16 dis keys ------------
  const int b = m0 >> 10;
  const float gA = gates[b*2+0], gD = gates[b*2+1];
  ushort_t* R = lds + w*8192;               // per-wave 16 KB region
  // K B-fragments straight from global: lane = token lr, dims (l>>4)*8
  const ushort_t* kbase = kv + ((size_t)b*NTOK + lr)*D_ + n0 + wc*64 + (l>>4)*8;
  bf16x8 kA0 = *(const bf16x8*)(kbase);
  bf16x8 kA1 = *(const bf16x8*)(kbase + 32);
  bf16x8 kD0 = *(const bf16x8*)(kbase + (size_t)2*B_*NTOK*D_);
  bf16x8 kD1 = *(const bf16x8*)(kbase + (size_t)2*B_*NTOK*D_ + 32);
  // QK^T: 8 chunks of 16 rows; q C->A transpose through 2x1KB LDS scratch
  f32x4 scA[8], scD[8];
  #pragma unroll
  for(int i=0;i<8;++i){ scA[i] = fz; scD[i] = fz; }
  #pragma unroll
  for(int i=0;i<8;++i){
    ushort_t* qs = R + (i&1)*1024;
    #pragma unroll
    for(int j=0;j<4;++j){
      #pragma unroll
      for(int r=0;r<4;++r){
        int row = (l>>4)*4 + r;            // row within 16-chunk
        int col = j*16 + lr;               // dim within head
        qs[row*64 + ((((col>>3) ^ (row&7))<<3) | (col&7))] = f2b(acc[i][j][r]);
      }
    }
    LGKM0();                               // cross-lane RAW: writes visible
    bf16x8 af0 = *(const bf16x8*)&qs[lr*64 + ((((l>>4))   ^ (lr&7))<<3)];
    bf16x8 af1 = *(const bf16x8*)&qs[lr*64 + (((4+(l>>4)) ^ (lr&7))<<3)];
    scA[i] = __builtin_amdgcn_mfma_f32_16x16x32_bf16(af0, kA0, scA[i], 0,0,0);
    scA[i] = __builtin_amdgcn_mfma_f32_16x16x32_bf16(af1, kA1, scA[i], 0,0,0);
    scD[i] = __builtin_amdgcn_mfma_f32_16x16x32_bf16(af0, kD0, scD[i], 0,0,0);
    scD[i] = __builtin_amdgcn_mfma_f32_16x16x32_bf16(af1, kD1, scD[i], 0,0,0);
  }
  // V loads issued now (acc regs free); latency hides under softmax VALU
  uint4 vld[4];
  #pragma unroll
  for(int it=0; it<4; ++it){
    int u = it*64 + l;
    int tp = u >> 3, c = u & 7;
    int tensor = (tp < 16) ? 1 : 3;
    int t = tp & 15;
    vld[it] = *(const uint4*)(kv + (((size_t)tensor*B_ + b)*NTOK + t)*D_
                                 + n0 + wc*64 + c*8);
  }
  // softmax over 16 keys (t = lane&15), per tensor, gated; P -> LDS (stride 44)
  LGKM0();                                  // last q-scratch reads done (WAR vs ps)
  #pragma unroll
  for(int i=0;i<8;++i){
    #pragma unroll
    for(int r=0;r<4;++r){
      float vA = scA[i][r]*SCALE_, vD = scD[i][r]*SCALE_;
      float mA = vA, mD = vD;
      #pragma unroll
      for(int off=1; off<16; off<<=1){
        mA = fmaxf(mA, __shfl_xor(mA, off));
        mD = fmaxf(mD, __shfl_xor(mD, off));
      }
      float eA = __expf(vA - mA), eD = __expf(vD - mD);
      float sA = eA, sD = eD;
      #pragma unroll
      for(int off=1; off<16; off<<=1){
        sA += __shfl_xor(sA, off);
        sD += __shfl_xor(sD, off);
      }
      int lrow = i*16 + (l>>4)*4 + r;
      R[lrow*44 + lr]      = f2b(gA*eA/sA);
      R[lrow*44 + 16 + lr] = f2b(gD*eD/sD);
    }
  }
  // scatter V^T: vts[d][t'] at R+5632, stride 40
  ushort_t* vts = R + 5632;
  #pragma unroll
  for(int it=0; it<4; ++it){
    int u = it*64 + l;
    int tp = u >> 3, c = u & 7;
    const ushort_t* pv = (const ushort_t*)&vld[it];
    #pragma unroll
    for(int e=0;e<8;++e) vts[(c*8+e)*40 + tp] = pv[e];
  }
  LGKM0();                                  // ps + vts visible across lanes
  // PV: P(128x32) @ V^T -> z, K=32 one MFMA per (i,j)
  bf16x8 pa[8], vb[4];
  #pragma unroll
  for(int i=0;i<8;++i) pa[i] = *(const bf16x8*)&R[(i*16+lr)*44 + (l>>4)*8];
  #pragma unroll
  for(int j=0;j<4;++j)  vb[j] = *(const bf16x8*)&vts[(j*16+lr)*40 + (l>>4)*8];
  f32x4 z[8][4];
  #pragma unroll
  for(int i=0;i<8;++i){
    #pragma unroll
    for(int j=0;j<4;++j)
      z[i][j] = __builtin_amdgcn_mfma_f32_16x16x32_bf16(pa[i], vb[j], fz, 0,0,0);
  }
  #pragma unroll
  for(int i=0;i<8;++i){
    #pragma unroll
    for(int j=0;j<4;++j){
      #pragma unroll
      for(int r=0;r<4;++r){
        int row = m0 + wr*128 + i*16 + (l>>4)*4 + r;
        int col = n0 + wc*64 + j*16 + lr;
        Z[(size_t)row*D_ + col] = f2b(z[i][j][r]);
      }
    }
  }
}

// ----------------------------------------------- gemm2: out-proj -----------
__global__ __launch_bounds__(512,2) void gemm2_8p(
      const ushort_t* __restrict__ Zin, const ushort_t* __restrict__ Wo,
      const float* __restrict__ bias, const float* __restrict__ resid,
      float* __restrict__ out){
  __shared__ __align__(16) ushort_t lds[81920];   // 160 KiB: A x3 | B x2
  const int lid = (blockIdx.x & 7)*80 + (blockIdx.x >> 3);
  const int m0 = (lid/5)*256, n0 = (lid%5)*256;
  const int tid = threadIdx.x, l = tid & 63, w = tid >> 6;
  const int wr = w >> 2, wc = w & 3;
  const int lr = l & 15;
  const int csw0 = ((l>>4)*8)    ^ ((l&7)<<3);
  const int csw1 = (32+(l>>4)*8) ^ ((l&7)<<3);
  const int bro  = (wc & 1)*64 + lr;
  const ushort_t* Asrc = Zin + (size_t)m0*D_;
  const ushort_t* Bsrc = Wo  + (size_t)n0*D_;
  const f32x4 fz = {0.f,0.f,0.f,0.f};
  f32x4 acc[8][4];
  #pragma unroll
  for(int i=0;i<8;++i){
    #pragma unroll
    for(int j=0;j<4;++j) acc[i][j] = fz;
  }
  bf16x8 a[4][2], bball[4][2];

  MAINLOOP5

  // epilogue: bias + residual, f32 out
  float bj[4];
  #pragma unroll
  for(int j=0;j<4;++j) bj[j] = bias[n0 + wc*64 + j*16 + lr];
  #pragma unroll
  for(int i=0;i<8;++i){
    #pragma unroll
    for(int j=0;j<4;++j){
      #pragma unroll
      for(int r=0;r<4;++r){
        int m = m0 + wr*128 + i*16 + (l>>4)*4 + r;
        int n = n0 + wc*64 + j*16 + lr;
        out[(size_t)m*D_ + n] = acc[i][j][r] + bj[j] + resid[(size_t)m*D_ + n];
      }
    }
  }
}

// --------------------------------------------------------------------------
extern "C" void kernel_launch(void* const* d_in, const int* in_sizes, int n_in,
                              void* d_out, int out_size, void* d_ws, size_t ws_size,
                              hipStream_t stream){
  const float* hidden = (const float*)d_in[0];
  const float* enc    = (const float*)d_in[1];
  const float* w_q    = (const float*)d_in[2];
  const float* w_k    = (const float*)d_in[3];
  const float* w_v    = (const float*)d_in[4];
  const float* w_kd   = (const float*)d_in[5];
  const float* w_vd   = (const float*)d_in[6];
  const float* w_gate = (const float*)d_in[7];
  const float* b_gate = (const float*)d_in[8];
  const float* aLog   = (const float*)d_in[9];
  const float* dLog   = (const float*)d_in[10];
  const float* w_out  = (const float*)d_in[11];
  const float* b_out  = (const float*)d_in[12];
  float* out = (float*)d_out;

  char* ws = (char*)d_ws;
  ushort_t* z_bf   = (ushort_t*)(ws + 0);           // 83,886,080 B
  ushort_t* kv_bf  = (ushort_t*)(ws + 83886080);    //  5,242,880 B
  ushort_t* wq_bf  = (ushort_t*)(ws + 89128960);    //  3,276,800 B
  ushort_t* wk_bf  = (ushort_t*)(ws + 92405760);    //  1,966,080 B
  ushort_t* wv_bf  = (ushort_t*)(ws + 94371840);    //  1,966,080 B
  ushort_t* wkd_bf = (ushort_t*)(ws + 96337920);    //  1,966,080 B
  ushort_t* wvd_bf = (ushort_t*)(ws + 98304000);    //  1,966,080 B
  ushort_t* wo_bf  = (ushort_t*)(ws + 100270080);   //  3,276,800 B
  ushort_t* enc_bf = (ushort_t*)(ws + 103546880);   //  2,359,296 B
  float*    gates  = (float*)   (ws + 105906176);   //        256 B

  // hidden bf16 lives in the FIRST HALF OF d_out (168 MB f32 buffer; gemm1
  // consumes it fully before gemm2 writes d_out — stream-ordered, safe).
  ushort_t* hid_bf = (ushort_t*)d_out;              // 83,886,080 B <= out bytes

  CvtArgs ca;
  ca.src[0]=w_q;   ca.dst[0]=wq_bf;  ca.n[0]=D_*D_;
  ca.src[1]=w_k;   ca.dst[1]=wk_bf;  ca.n[1]=D_*CROSS_;
  ca.src[2]=w_v;   ca.dst[2]=wv_bf;  ca.n[2]=D_*CROSS_;
  ca.src[3]=w_kd;  ca.dst[3]=wkd_bf; ca.n[3]=D_*CROSS_;
  ca.src[4]=w_vd;  ca.dst[4]=wvd_bf; ca.n[4]=D_*CROSS_;
  ca.src[5]=w_out; ca.dst[5]=wo_bf;  ca.n[5]=D_*D_;
  ca.src[6]=enc;   ca.dst[6]=enc_bf; ca.n[6]=B_*48*CROSS_;
  cvt_kernel<<<dim3(1600,7), 256, 0, stream>>>(ca);
  cvt_big<<<20480, 256, 0, stream>>>(hidden, hid_bf, B_*S_*D_);

  gates_kernel<<<32, 256, 0, stream>>>(enc, w_gate, b_gate, aLog, dLog, gates);
  kv_gemm<<<dim3(4,10,4), 256, 0, stream>>>(enc_bf, wk_bf, wv_bf, wkd_bf, wvd_bf, kv_bf);
  gemm1_attn_8p<<<640, 512, 0, stream>>>(hid_bf, wq_bf, kv_bf, gates, z_bf);
  gemm2_8p<<<640, 512, 0, stream>>>(z_bf, wo_bf, b_out, hidden, out);
}